// Round 6
// baseline (1492.451 us; speedup 1.0000x reference)
//
#include <hip/hip_runtime.h>
#include <math.h>
#include <stdint.h>

#define BATCH 4096
#define MCAND 50
#define NTOP 32
#define HID 100
#define TFL 20200                  /* floats per (T1,T2) table: 101*100*2 */

#define MINVC  (-0x1.fffffep-1f)   /* nextafter(-1,0) */
#define SQRT2C (0x1.6a09e6p+0f)    /* fp32 sqrt(2) */

__device__ __forceinline__ uint32_t rotl32(uint32_t v, int d){ return (v<<d)|(v>>(32-d)); }

// JAX threefry2x32 core (20 rounds, 5 key injections)
__device__ __forceinline__ void tf2x32(uint32_t k0, uint32_t k1, uint32_t x0, uint32_t x1,
                                       uint32_t &o0, uint32_t &o1){
  uint32_t k2 = k0 ^ k1 ^ 0x1BD11BDAu;
  x0 += k0; x1 += k1;
#define RND(r) { x0 += x1; x1 = rotl32(x1,(r)); x1 ^= x0; }
  RND(13) RND(15) RND(26) RND(6)
  x0 += k1; x1 += k2 + 1u;
  RND(17) RND(29) RND(16) RND(24)
  x0 += k2; x1 += k0 + 2u;
  RND(13) RND(15) RND(26) RND(6)
  x0 += k0; x1 += k1 + 3u;
  RND(17) RND(29) RND(16) RND(24)
  x0 += k1; x1 += k2 + 4u;
  RND(13) RND(15) RND(26) RND(6)
  x0 += k2; x1 += k0 + 5u;
#undef RND
  o0 = x0; o1 = x1;
}

// XLA ErfInv32 (Giles). w = -log1p(-x*x)
__device__ __forceinline__ float erfinv32(float x){
  float w = -log1pf(-x*x);
  float p;
  if (w < 5.0f){
    w = w - 2.5f;
    p = 2.81022636e-08f;
    p = fmaf(p, w, 3.43273939e-07f);
    p = fmaf(p, w, -3.5233877e-06f);
    p = fmaf(p, w, -4.39150654e-06f);
    p = fmaf(p, w, 0.00021858087f);
    p = fmaf(p, w, -0.00125372503f);
    p = fmaf(p, w, -0.00417768164f);
    p = fmaf(p, w, 0.246640727f);
    p = fmaf(p, w, 1.50140941f);
  } else {
    w = sqrtf(w) - 3.0f;
    p = -0.000200214257f;
    p = fmaf(p, w, 0.000100950558f);
    p = fmaf(p, w, 0.00134934322f);
    p = fmaf(p, w, -0.00367342844f);
    p = fmaf(p, w, 0.00573950773f);
    p = fmaf(p, w, -0.0076224613f);
    p = fmaf(p, w, 0.00943887047f);
    p = fmaf(p, w, 1.00167406f);
    p = fmaf(p, w, 2.83297682f);
  }
  return p*x;
}

// ---- VALU-only lane exchanges (no DS pipe) ----
#define DPPF(v, CTRL) __int_as_float(__builtin_amdgcn_update_dpp( \
    0, __float_as_int(v), (CTRL), 0xF, 0xF, true))
#define DPPI(v, CTRL) __builtin_amdgcn_update_dpp(0, (v), (CTRL), 0xF, 0xF, true)
#define DPPADD(v, CTRL) ((v) + DPPF((v), (CTRL)))

__device__ __forceinline__ float fswap4(float v){        // v[lane^4]
  float a = DPPF(v, 0x114);   // row_shr:4
  float b = DPPF(v, 0x104);   // row_shl:4
  return (threadIdx.x & 4) ? a : b;
}
__device__ __forceinline__ int iswap4(int v){
  int a = DPPI(v, 0x114), b = DPPI(v, 0x104);
  return (threadIdx.x & 4) ? a : b;
}
__device__ __forceinline__ float fswap8(float v){        // v[lane^8] = row_ror:8
  return DPPF(v, 0x128);
}
__device__ __forceinline__ float fswap16(float v){       // v[lane^16]
#if __has_builtin(__builtin_amdgcn_permlane16_swap)
  auto r = __builtin_amdgcn_permlane16_swap(__float_as_uint(v), __float_as_uint(v), false, false);
  return __uint_as_float((threadIdx.x & 16) ? r[0] : r[1]);
#else
  return __shfl_xor(v, 16, 64);
#endif
}
__device__ __forceinline__ float fswap32(float v){       // v[lane^32]
#if __has_builtin(__builtin_amdgcn_permlane32_swap)
  auto r = __builtin_amdgcn_permlane32_swap(__float_as_uint(v), __float_as_uint(v), false, false);
  return __uint_as_float((threadIdx.x & 32) ? r[0] : r[1]);
#else
  return __shfl_xor(v, 32, 64);
#endif
}

// ---------------------------------------------------------------------------
// Piecewise-linear CEM, PAIRED anti-phase schedule (r5 resubmission; r5's
// bench failed at the container level with no evidence the kernel ran;
// defensive delta: plain __launch_bounds__(1024), everything else identical).
//
//   h2pre[n] = T1[r][n] + a*T2[r][n],  r = #{t_k < a}  (prefix tables, fp32)
//
// TWO batch elements per 1024-thread block (el = tid>>9). Their phases are
// interleaved at every barrier: interval i runs
//     gather(element with i&1==el) || stats(other element)
// so the block-wide barrier acts as an enforced anti-phase scheduler: every
// interval has ~6 gather waves + 1 stats wave + 1 RNG wave active, instead
// of r3/r4's G -> bar -> S with 7/8 waves idle during S.
//   element e: gather(t) at interval 2t+e, stats(t) at interval 2t+1+e.
// RNG: per-t key pairs precomputed ONCE into LDS (792 B); in-loop eps is one
// threefry + erfinv on the idle wave (w8==7) of each element. Loop does zero
// global memory traffic.
// LDS: 2 tables (161,600) + A/QB/EPB (1,200) + keys (792) = 163,592 B
//      <= 163,840 (full 160 KiB pool), 1 block/CU, 16 waves.
// ---------------------------------------------------------------------------
__global__ __launch_bounds__(1024) void cem_kernel(
    const float* __restrict__ states, const float* __restrict__ W1,
    const float* __restrict__ b1,     const float* __restrict__ W2,
    const float* __restrict__ b2,     const float* __restrict__ W3,
    const float* __restrict__ b3,     float* __restrict__ out)
{
  __shared__ __align__(16) float smem[40898];            // 163,592 B
  const int tid  = threadIdx.x;
  const int el   = tid >> 9;            // element 0 / 1
  const int lt   = tid & 511;           // local tid within element
  const int w8   = lt >> 6;             // local wave 0..7
  const int lane = tid & 63;
  const int gc   = lt >> 3;             // gather candidate (8 lanes/cand)
  const int gj   = lt & 7;
  const bool gact = (lt < 8*MCAND);     // lt < 400
  const int b    = 2*blockIdx.x + el;

  float*  const Tb   = smem + el*TFL;   // this element's table
  float2* const T2D  = (float2*)Tb;     // [101][100] (T1,T2)
  int*    const ORD  = (int*)(Tb + 300);   // init scratch (inside T)
  float*  const STm  = Tb + 400;           // init scratch (inside T)
  float*  const Aang = smem + 2*TFL       + el*50;   // [50] angles
  float*  const QB   = smem + 2*TFL + 100 + el*50;   // [50] q values
  float*  const EPB  = smem + 2*TFL + 200 + el*50;   // [50] eps
  uint32_t* const sKeys = (uint32_t*)(smem + 2*TFL + 300); // [198] shared

  // per-thread W3 slice for the gather (n = gj + 8i)
  float w3r[13];
#pragma unroll
  for (int i = 0; i < 13; ++i){
    int n = gj + (i<<3);
    w3r[i] = (n < HID) ? W3[n] : 0.0f;
  }
  const float sB3v = b3[0];

  // ---------- init P0: u, v, thresholds; angles0; key table ----------
  if (lt < HID){
    float u = fmaf(states[2*b], W1[lt], fmaf(states[2*b+1], W1[HID+lt], b1[lt]));
    float v = W1[2*HID+lt];
    float tt = (v != 0.0f) ? (-u / v) : INFINITY;
    Tb[lt]     = u;
    Tb[HID+lt] = v;
    Tb[200+lt] = tt;
  }
  if (lt >= 128 && lt < 128 + MCAND){
    // iteration-0 uniform angles (mu=0, std=1)
    int c = lt - 128;
    uint32_t A0, B0, a1t, b1t;
    tf2x32(0u,42u,0u,2u,A0,a1t);
    tf2x32(0u,42u,1u,3u,B0,b1t);
    uint32_t gidx = (uint32_t)b*MCAND + (uint32_t)c;
    uint32_t r0,r1,bits;
    if (gidx < 102400u){ tf2x32(A0,B0,gidx,gidx+102400u,r0,r1); bits = r0; }
    else               { tf2x32(A0,B0,gidx-102400u,gidx,r0,r1); bits = r1; }
    Aang[c] = __uint_as_float((bits>>9) | 0x3f800000u) - 1.0f;
  }
  if (el == 0 && lt >= 256 && lt < 256 + 99){
    // keys[j] of split(kloop, 99): concat layout (r1-proven bit-identical)
    int j = lt - 256;
    uint32_t A0, B0, A1, B1;
    tf2x32(0u,42u,0u,2u,A0,A1);
    tf2x32(0u,42u,1u,3u,B0,B1);
    uint32_t o0,o1;
    tf2x32(A1,B1,(uint32_t)j,(uint32_t)(99+j),o0,o1);
    sKeys[j]    = o0;
    sKeys[99+j] = o1;
  }
  __syncthreads();

  // ---------- init P1: stable rank-by-count, scatter sorted ----------
  if (lt < HID){
    float tk = Tb[200+lt];
    int rk = 0;
    for (int j2 = 0; j2 < HID; ++j2){
      float tj = Tb[200+j2];
      rk += (tj < tk || (tj == tk && j2 < lt)) ? 1 : 0;
    }
    float u = Tb[lt], v = Tb[HID+lt];
    // neg-type: active iff a < t (v<0, or v==0 with u>0 -> always active, t=+inf)
    int neg = (v < 0.0f || (v == 0.0f && u > 0.0f)) ? 1 : 0;
    STm[rk] = tk;
    ORD[rk] = lt | (neg << 7);
  }
  __syncthreads();

  // ---------- init P1.5: builder meta -> regs; thresholds -> regs ----------
  int kpA = 0, kpB = 0; float cuA = 0.f, cvA = 0.f, cuB = 0.f, cvB = 0.f;
  if (w8 == 0){
    kpA = ORD[lane];
    int kiA = kpA & 127;
    float uA = Tb[kiA], vA = Tb[HID+kiA];
    cuA = (kpA & 128) ? -uA : uA;     // signed delta for prefix pass
    cvA = (kpA & 128) ? -vA : vA;
    if (lane < 36){
      kpB = ORD[64+lane];
      int kiB = kpB & 127;
      float uB = Tb[kiB], vB = Tb[HID+kiB];
      cuB = (kpB & 128) ? -uB : uB;
      cvB = (kpB & 128) ? -vB : vB;
    }
  }
  float st_r[13];                       // loop-invariant thresholds in regs
#pragma unroll
  for (int i = 0; i < 13; ++i){
    int idx = gj*13 + i;
    st_r[i] = (idx < HID) ? STm[idx] : INFINITY;
  }
  __syncthreads();   // meta/thresholds consumed; T scratch region now dead

  // ---------- init P2: wave w8==0 of each element builds its prefix table ----------
  if (w8 == 0){
    const int L = lane;          // columns n=L and n=64+L (L<36)
    float a10 = b2[L], a20 = 0.0f;
    float a11 = (L < 36) ? b2[64+L] : 0.0f, a21 = 0.0f;
    // pass 1: rank-0 base = b2 + sum over neg-type features of (+u,+v)*W2row
#pragma unroll 8
    for (int rr = 0; rr < 64; ++rr){
      int   kp = __builtin_amdgcn_readlane(kpA, rr);
      float cu = __int_as_float(__builtin_amdgcn_readlane(__float_as_int(cuA), rr));
      float cv = __int_as_float(__builtin_amdgcn_readlane(__float_as_int(cvA), rr));
      int k = kp & 127;
      float bu = (kp & 128) ? -cu : 0.0f;  // = +u for neg-type, 0 for pos-type
      float bv = (kp & 128) ? -cv : 0.0f;
      float w0 = W2[k*HID + L];
      a10 = fmaf(bu, w0, a10); a20 = fmaf(bv, w0, a20);
      if (L < 36){
        float w1 = W2[k*HID + 64+L];
        a11 = fmaf(bu, w1, a11); a21 = fmaf(bv, w1, a21);
      }
    }
#pragma unroll 6
    for (int rr = 0; rr < 36; ++rr){
      int   kp = __builtin_amdgcn_readlane(kpB, rr);
      float cu = __int_as_float(__builtin_amdgcn_readlane(__float_as_int(cuB), rr));
      float cv = __int_as_float(__builtin_amdgcn_readlane(__float_as_int(cvB), rr));
      int k = kp & 127;
      float bu = (kp & 128) ? -cu : 0.0f;
      float bv = (kp & 128) ? -cv : 0.0f;
      float w0 = W2[k*HID + L];
      a10 = fmaf(bu, w0, a10); a20 = fmaf(bv, w0, a20);
      if (L < 36){
        float w1 = W2[k*HID + 64+L];
        a11 = fmaf(bu, w1, a11); a21 = fmaf(bv, w1, a21);
      }
    }
    { float2 f; f.x = a10; f.y = a20; T2D[L] = f; }
    if (L < 36){ float2 f; f.x = a11; f.y = a21; T2D[64+L] = f; }
    // pass 2: ascending ranks, signed deltas, write T[rr+1]
#pragma unroll 8
    for (int rr = 0; rr < 64; ++rr){
      int   kp = __builtin_amdgcn_readlane(kpA, rr);
      float cu = __int_as_float(__builtin_amdgcn_readlane(__float_as_int(cuA), rr));
      float cv = __int_as_float(__builtin_amdgcn_readlane(__float_as_int(cvA), rr));
      int k = kp & 127;
      float w0 = W2[k*HID + L];
      a10 = fmaf(cu, w0, a10); a20 = fmaf(cv, w0, a20);
      { float2 f; f.x = a10; f.y = a20; T2D[(rr+1)*HID + L] = f; }
      if (L < 36){
        float w1 = W2[k*HID + 64+L];
        a11 = fmaf(cu, w1, a11); a21 = fmaf(cv, w1, a21);
        float2 f; f.x = a11; f.y = a21; T2D[(rr+1)*HID + 64+L] = f;
      }
    }
#pragma unroll 6
    for (int rr = 0; rr < 36; ++rr){
      int   kp = __builtin_amdgcn_readlane(kpB, rr);
      float cu = __int_as_float(__builtin_amdgcn_readlane(__float_as_int(cuB), rr));
      float cv = __int_as_float(__builtin_amdgcn_readlane(__float_as_int(cvB), rr));
      int k = kp & 127;
      float w0 = W2[k*HID + L];
      a10 = fmaf(cu, w0, a10); a20 = fmaf(cv, w0, a20);
      { float2 f; f.x = a10; f.y = a20; T2D[(65+rr)*HID + L] = f; }
      if (L < 36){
        float w1 = W2[k*HID + 64+L];
        a11 = fmaf(cu, w1, a11); a21 = fmaf(cv, w1, a21);
        float2 f; f.x = a11; f.y = a21; T2D[(65+rr)*HID + 64+L] = f;
      }
    }
  }
  __syncthreads();   // tables + angles0 + keys all visible

  // ---------- paired CEM loop: 199 intervals, ONE barrier each ----------
  // element e: gather(t) at interval 2t+e, stats(t) at interval 2t+1+e.
#pragma unroll 1
  for (int i = 0; i < 199; ++i){
    if ((i & 1) == el){
      const int t = (i - el) >> 1;
      if (t < 99){
        // --- G: q_c = sum_n relu(T1[r][n] + a*T2[r][n]) * W3[n] ---
        if (gact){
          const float av = Aang[gc];      // LDS broadcast (8 lanes same addr)
          int rk = 0;
#pragma unroll
          for (int i2 = 0; i2 < 13; ++i2) rk += (st_r[i2] < av) ? 1 : 0;
          rk += DPPI(rk, 0xB1);
          rk += DPPI(rk, 0x4E);
          rk += iswap4(rk);
          const float2* __restrict__ Trow = T2D + rk*HID;
          float acc = 0.0f;
#pragma unroll
          for (int i2 = 0; i2 < 13; ++i2){
            int n = gj + (i2<<3);
            n = (n < HID) ? n : gj;       // clamp (w3r=0 there)
            float2 tv = Trow[n];
            float h = fmaxf(fmaf(av, tv.y, tv.x), 0.0f);
            acc = fmaf(h, w3r[i2], acc);
          }
          acc = DPPADD(acc, 0xB1);
          acc = DPPADD(acc, 0x4E);
          acc += fswap4(acc);
          if (gj == 0) QB[gc] = acc;
        }
        // --- eps(t+1) on the idle wave (keys from LDS, 1 threefry) ---
        if (w8 == 7 && t < 98 && lane < MCAND){
          uint32_t kk0 = sKeys[2*t], kk1 = sKeys[2*t+1];
          uint32_t gidx = (uint32_t)b*MCAND + (uint32_t)lane;
          uint32_t r0, r1, bits;
          if (gidx < 102400u){ tf2x32(kk0,kk1,gidx,gidx+102400u,r0,r1); bits = r0; }
          else               { tf2x32(kk0,kk1,gidx-102400u,gidx,r0,r1); bits = r1; }
          float fl = __uint_as_float((bits>>9) | 0x3f800000u) - 1.0f;
          float u  = fmaxf(MINVC, fl*2.0f + MINVC);
          EPB[lane] = SQRT2C * erfinv32(u);
        }
      }
    } else {
      const int t = (i - 1 - el) >> 1;
      if (t >= 0 && w8 == 0){
        // --- S: top-32 stats (VALU bitonic), write a(t+1) ---
        float q = (lane < MCAND) ? (QB[lane] + sB3v) : -INFINITY;
        float v = q;
#define BST(KK, JJ, PV) { float pv = (PV); bool lower = (lane & (JJ)) == 0; \
        bool asc = (lane & (KK)) != 0; float mn = fminf(v, pv), mx = fmaxf(v, pv); \
        v = (lower == asc) ? mn : mx; }
        BST(2, 1,  DPPF(v, 0xB1))
        BST(4, 2,  DPPF(v, 0x4E))
        BST(4, 1,  DPPF(v, 0xB1))
        BST(8, 4,  fswap4(v))
        BST(8, 2,  DPPF(v, 0x4E))
        BST(8, 1,  DPPF(v, 0xB1))
        BST(16, 8, fswap8(v))
        BST(16, 4, fswap4(v))
        BST(16, 2, DPPF(v, 0x4E))
        BST(16, 1, DPPF(v, 0xB1))
        BST(32, 16, fswap16(v))
        BST(32, 8,  fswap8(v))
        BST(32, 4,  fswap4(v))
        BST(32, 2,  DPPF(v, 0x4E))
        BST(32, 1,  DPPF(v, 0xB1))
#undef BST
        {
          float pv = fswap32(v);
          v = ((lane & 32) == 0) ? fmaxf(v, pv) : fminf(v, pv);
        }
        // sum / sum-of-squares over lanes 0..31 (same add order as r2/r3)
        float sv = (lane < NTOP) ? v : 0.0f;
        sv += fswap32(sv);
        sv += fswap16(sv);
        sv += fswap8(sv);
        sv += fswap4(sv);
        sv = DPPADD(sv, 0x4E);
        sv = DPPADD(sv, 0xB1);
        float mun = sv / 32.0f;
        float dv = (lane < NTOP) ? (v - mun) : 0.0f;
        float s2 = dv*dv;
        s2 += fswap32(s2);
        s2 += fswap16(s2);
        s2 += fswap8(s2);
        s2 += fswap4(s2);
        s2 = DPPADD(s2, 0x4E);
        s2 = DPPADD(s2, 0xB1);
        float stdv = sqrtf(s2 / 31.0f);
        if (t == 98){
          if (lane == 0) out[b] = mun * 6.2831854820251465f;  // fp32(2*pi)
        } else if (lane < MCAND){
          Aang[lane] = fmaf(stdv, EPB[lane], mun);            // a(t+1)
        }
      }
    }
    __syncthreads();
    // race-freedom: for element e, QB written @2t+e, read @2t+1+e, rewritten
    // @2t+2+e; Aang written @2t+1+e, read @2t+2+e; EPB written @2t+e, read
    // @2t+1+e, rewritten @2t+2+e — each producer/consumer pair is separated
    // by exactly one block-wide barrier.
  }
}

extern "C" void kernel_launch(void* const* d_in, const int* in_sizes, int n_in,
                              void* d_out, int out_size, void* d_ws, size_t ws_size,
                              hipStream_t stream) {
  const float* states = (const float*)d_in[0];
  const float* W1     = (const float*)d_in[1];
  const float* b1     = (const float*)d_in[2];
  const float* W2     = (const float*)d_in[3];
  const float* b2     = (const float*)d_in[4];
  const float* W3     = (const float*)d_in[5];
  const float* b3     = (const float*)d_in[6];
  float* out = (float*)d_out;
  hipLaunchKernelGGL(cem_kernel, dim3(BATCH/2), dim3(1024), 0, stream,
                     states, W1, b1, W2, b2, W3, b3, out);
}

// Round 7
// 1383.435 us; speedup vs baseline: 1.0788x; 1.0788x over previous
//
#include <hip/hip_runtime.h>
#include <math.h>
#include <stdint.h>

#define BATCH 4096
#define MCAND 50
#define NTOP 32
#define HID 100
#define TFL 20200                  /* floats per (T1,T2) table: 101*100*2 */

#define MINVC  (-0x1.fffffep-1f)   /* nextafter(-1,0) */
#define SQRT2C (0x1.6a09e6p+0f)    /* fp32 sqrt(2) */

__device__ __forceinline__ uint32_t rotl32(uint32_t v, int d){ return (v<<d)|(v>>(32-d)); }

// JAX threefry2x32 core (20 rounds, 5 key injections)
__device__ __forceinline__ void tf2x32(uint32_t k0, uint32_t k1, uint32_t x0, uint32_t x1,
                                       uint32_t &o0, uint32_t &o1){
  uint32_t k2 = k0 ^ k1 ^ 0x1BD11BDAu;
  x0 += k0; x1 += k1;
#define RND(r) { x0 += x1; x1 = rotl32(x1,(r)); x1 ^= x0; }
  RND(13) RND(15) RND(26) RND(6)
  x0 += k1; x1 += k2 + 1u;
  RND(17) RND(29) RND(16) RND(24)
  x0 += k2; x1 += k0 + 2u;
  RND(13) RND(15) RND(26) RND(6)
  x0 += k0; x1 += k1 + 3u;
  RND(17) RND(29) RND(16) RND(24)
  x0 += k1; x1 += k2 + 4u;
  RND(13) RND(15) RND(26) RND(6)
  x0 += k2; x1 += k0 + 5u;
#undef RND
  o0 = x0; o1 = x1;
}

// XLA ErfInv32 (Giles). w = -log1p(-x*x)
__device__ __forceinline__ float erfinv32(float x){
  float w = -log1pf(-x*x);
  float p;
  if (w < 5.0f){
    w = w - 2.5f;
    p = 2.81022636e-08f;
    p = fmaf(p, w, 3.43273939e-07f);
    p = fmaf(p, w, -3.5233877e-06f);
    p = fmaf(p, w, -4.39150654e-06f);
    p = fmaf(p, w, 0.00021858087f);
    p = fmaf(p, w, -0.00125372503f);
    p = fmaf(p, w, -0.00417768164f);
    p = fmaf(p, w, 0.246640727f);
    p = fmaf(p, w, 1.50140941f);
  } else {
    w = sqrtf(w) - 3.0f;
    p = -0.000200214257f;
    p = fmaf(p, w, 0.000100950558f);
    p = fmaf(p, w, 0.00134934322f);
    p = fmaf(p, w, -0.00367342844f);
    p = fmaf(p, w, 0.00573950773f);
    p = fmaf(p, w, -0.0076224613f);
    p = fmaf(p, w, 0.00943887047f);
    p = fmaf(p, w, 1.00167406f);
    p = fmaf(p, w, 2.83297682f);
  }
  return p*x;
}

// ---- VALU-only lane exchanges (no DS pipe) ----
#define DPPF(v, CTRL) __int_as_float(__builtin_amdgcn_update_dpp( \
    0, __float_as_int(v), (CTRL), 0xF, 0xF, true))
#define DPPI(v, CTRL) __builtin_amdgcn_update_dpp(0, (v), (CTRL), 0xF, 0xF, true)
#define DPPADD(v, CTRL) ((v) + DPPF((v), (CTRL)))

__device__ __forceinline__ float fswap4(float v){        // v[lane^4]
  float a = DPPF(v, 0x114);   // row_shr:4
  float b = DPPF(v, 0x104);   // row_shl:4
  return (threadIdx.x & 4) ? a : b;
}
__device__ __forceinline__ int iswap4(int v){
  int a = DPPI(v, 0x114), b = DPPI(v, 0x104);
  return (threadIdx.x & 4) ? a : b;
}
__device__ __forceinline__ float fswap8(float v){        // v[lane^8] = row_ror:8
  return DPPF(v, 0x128);
}
__device__ __forceinline__ float fswap16(float v){       // v[lane^16]
#if __has_builtin(__builtin_amdgcn_permlane16_swap)
  auto r = __builtin_amdgcn_permlane16_swap(__float_as_uint(v), __float_as_uint(v), false, false);
  return __uint_as_float((threadIdx.x & 16) ? r[0] : r[1]);
#else
  return __shfl_xor(v, 16, 64);
#endif
}
__device__ __forceinline__ float fswap32(float v){       // v[lane^32]
#if __has_builtin(__builtin_amdgcn_permlane32_swap)
  auto r = __builtin_amdgcn_permlane32_swap(__float_as_uint(v), __float_as_uint(v), false, false);
  return __uint_as_float((threadIdx.x & 32) ? r[0] : r[1]);
#else
  return __shfl_xor(v, 32, 64);
#endif
}

// ---------------------------------------------------------------------------
// Piecewise-linear CEM — r3 topology (512-thread blocks, 2 independent
// blocks/CU filling each other's stalls) + zero-global-traffic RNG.
//
//   h2pre[n] = T1[r][n] + a*T2[r][n],  r = #{t_k < a}  (prefix tables, fp32)
//
// Loop (2 barriers):
//   G: waves 0-6 gather q(t) (float2 column slices, r3 order);
//      wave7 computes eps(t+1) from per-t keys HELD IN REGISTERS.
//   B1;  S: wave0 top-32 mu/std (VALU bitonic) -> AQ[] = a(t+1);
//        wave7 (idle otherwise) recomputes keys kk(t+1) redundantly per lane.
//   B2.
// No eps table, no workspace, no per-iteration global loads -> no vmcnt
// drain at B1 (r3's ~300us stall). AQ merges angles+q (read-then-write is
// wave-lockstep safe; group g is touched only by its own wave).
// LDS: table 20,200 + AQ 50 + EPB 50 = 20,300 floats = 81,200 B
//      -> 2 blocks/CU (162.4KB of the 160KiB pool).
// ---------------------------------------------------------------------------
__global__ __launch_bounds__(512) void cem_kernel(
    const float* __restrict__ states, const float* __restrict__ W1,
    const float* __restrict__ b1,     const float* __restrict__ W2,
    const float* __restrict__ b2,     const float* __restrict__ W3,
    const float* __restrict__ b3,     float* __restrict__ out)
{
  __shared__ __align__(16) float smem[20300];           // 81,200 B
  float*  const Tb   = smem;                            // table region
  float2* const T2D  = (float2*)Tb;                     // [101][100] (T1,T2)
  int*    const ORD  = (int*)(Tb + 300);                // init scratch (in T)
  float*  const STm  = Tb + 400;                        // init scratch (in T)
  float*  const AQ   = smem + 20200;                    // [50] angles <-> q
  float*  const EPB  = smem + 20250;                    // [50] eps

  const int tid  = threadIdx.x;
  const int b    = blockIdx.x;
  const int wv   = tid >> 6;
  const int lane = tid & 63;
  const int gc   = tid >> 3;            // gather candidate (8 lanes/cand)
  const int gj   = tid & 7;
  const bool gact = (tid < 8*MCAND);    // tid < 400 (waves 0-6)

  // per-thread W3 slice for the gather (n = gj + 8i)
  float w3r[13];
#pragma unroll
  for (int i = 0; i < 13; ++i){
    int n = gj + (i<<3);
    w3r[i] = (n < HID) ? W3[n] : 0.0f;
  }
  const float sB3v = b3[0];

  // wave7 register state: kloop key halves + current per-t key pair
  uint32_t A1k = 0u, B1k = 0u, kk0 = 0u, kk1 = 0u;

  // ---------- init P0: u,v,thresholds; angles0; wave7 key state ----------
  if (tid < HID){
    float u = fmaf(states[2*b], W1[tid], fmaf(states[2*b+1], W1[HID+tid], b1[tid]));
    float v = W1[2*HID+tid];
    float tt = (v != 0.0f) ? (-u / v) : INFINITY;
    Tb[tid]     = u;
    Tb[HID+tid] = v;
    Tb[200+tid] = tt;
  }
  if (tid >= 128 && tid < 128 + MCAND){
    // iteration-0 uniform angles (mu=0, std=1)
    int c = tid - 128;
    uint32_t A0, B0, a1t, b1t;
    tf2x32(0u,42u,0u,2u,A0,a1t);
    tf2x32(0u,42u,1u,3u,B0,b1t);
    uint32_t gidx = (uint32_t)b*MCAND + (uint32_t)c;
    uint32_t r0,r1,bits;
    if (gidx < 102400u){ tf2x32(A0,B0,gidx,gidx+102400u,r0,r1); bits = r0; }
    else               { tf2x32(A0,B0,gidx-102400u,gidx,r0,r1); bits = r1; }
    AQ[c] = __uint_as_float((bits>>9) | 0x3f800000u) - 1.0f;
  }
  if (wv == 7){
    // kloop = (A1,B1); kk pair for t=0 (keys[j] = concat[j] of split(kloop,99))
    uint32_t A0, B0;
    tf2x32(0u,42u,0u,2u,A0,A1k);
    tf2x32(0u,42u,1u,3u,B0,B1k);
    { uint32_t i0 = 0u; uint32_t x,y; tf2x32(A1k,B1k, i0, 99u+i0, x, y); kk0 = x; }
    { uint32_t i1 = 1u; uint32_t x,y; tf2x32(A1k,B1k, i1, 99u+i1, x, y); kk1 = x; }
  }
  __syncthreads();

  // ---------- init P1: stable rank-by-count, scatter sorted ----------
  if (tid < HID){
    float tk = Tb[200+tid];
    int rk = 0;
    for (int j2 = 0; j2 < HID; ++j2){
      float tj = Tb[200+j2];
      rk += (tj < tk || (tj == tk && j2 < tid)) ? 1 : 0;
    }
    float u = Tb[tid], v = Tb[HID+tid];
    // neg-type: active iff a < t (v<0, or v==0 with u>0 -> always active, t=+inf)
    int neg = (v < 0.0f || (v == 0.0f && u > 0.0f)) ? 1 : 0;
    STm[rk] = tk;
    ORD[rk] = tid | (neg << 7);
  }
  __syncthreads();

  // ---------- init P1.5: builder meta -> regs (wave0); thresholds -> regs ----------
  int kpA = 0, kpB = 0; float cuA = 0.f, cvA = 0.f, cuB = 0.f, cvB = 0.f;
  if (wv == 0){
    kpA = ORD[lane];
    int kiA = kpA & 127;
    float uA = Tb[kiA], vA = Tb[HID+kiA];
    cuA = (kpA & 128) ? -uA : uA;     // signed delta for prefix pass
    cvA = (kpA & 128) ? -vA : vA;
    if (lane < 36){
      kpB = ORD[64+lane];
      int kiB = kpB & 127;
      float uB = Tb[kiB], vB = Tb[HID+kiB];
      cuB = (kpB & 128) ? -uB : uB;
      cvB = (kpB & 128) ? -vB : vB;
    }
  }
  float st_r[13];                       // loop-invariant thresholds in regs
#pragma unroll
  for (int i = 0; i < 13; ++i){
    int idx = gj*13 + i;
    st_r[i] = (idx < HID) ? STm[idx] : INFINITY;
  }
  __syncthreads();   // meta/thresholds consumed; T scratch region now dead

  // ---------- init P2: wave0 builds the 101-row prefix table ----------
  if (wv == 0){
    const int L = lane;          // columns n=L and n=64+L (L<36)
    float a10 = b2[L], a20 = 0.0f;
    float a11 = (L < 36) ? b2[64+L] : 0.0f, a21 = 0.0f;
    // pass 1: rank-0 base = b2 + sum over neg-type features of (+u,+v)*W2row
#pragma unroll 8
    for (int rr = 0; rr < 64; ++rr){
      int   kp = __builtin_amdgcn_readlane(kpA, rr);
      float cu = __int_as_float(__builtin_amdgcn_readlane(__float_as_int(cuA), rr));
      float cv = __int_as_float(__builtin_amdgcn_readlane(__float_as_int(cvA), rr));
      int k = kp & 127;
      float bu = (kp & 128) ? -cu : 0.0f;  // = +u for neg-type, 0 for pos-type
      float bv = (kp & 128) ? -cv : 0.0f;
      float w0 = W2[k*HID + L];
      a10 = fmaf(bu, w0, a10); a20 = fmaf(bv, w0, a20);
      if (L < 36){
        float w1 = W2[k*HID + 64+L];
        a11 = fmaf(bu, w1, a11); a21 = fmaf(bv, w1, a21);
      }
    }
#pragma unroll 6
    for (int rr = 0; rr < 36; ++rr){
      int   kp = __builtin_amdgcn_readlane(kpB, rr);
      float cu = __int_as_float(__builtin_amdgcn_readlane(__float_as_int(cuB), rr));
      float cv = __int_as_float(__builtin_amdgcn_readlane(__float_as_int(cvB), rr));
      int k = kp & 127;
      float bu = (kp & 128) ? -cu : 0.0f;
      float bv = (kp & 128) ? -cv : 0.0f;
      float w0 = W2[k*HID + L];
      a10 = fmaf(bu, w0, a10); a20 = fmaf(bv, w0, a20);
      if (L < 36){
        float w1 = W2[k*HID + 64+L];
        a11 = fmaf(bu, w1, a11); a21 = fmaf(bv, w1, a21);
      }
    }
    { float2 f; f.x = a10; f.y = a20; T2D[L] = f; }
    if (L < 36){ float2 f; f.x = a11; f.y = a21; T2D[64+L] = f; }
    // pass 2: ascending ranks, signed deltas, write T[rr+1]
#pragma unroll 8
    for (int rr = 0; rr < 64; ++rr){
      int   kp = __builtin_amdgcn_readlane(kpA, rr);
      float cu = __int_as_float(__builtin_amdgcn_readlane(__float_as_int(cuA), rr));
      float cv = __int_as_float(__builtin_amdgcn_readlane(__float_as_int(cvA), rr));
      int k = kp & 127;
      float w0 = W2[k*HID + L];
      a10 = fmaf(cu, w0, a10); a20 = fmaf(cv, w0, a20);
      { float2 f; f.x = a10; f.y = a20; T2D[(rr+1)*HID + L] = f; }
      if (L < 36){
        float w1 = W2[k*HID + 64+L];
        a11 = fmaf(cu, w1, a11); a21 = fmaf(cv, w1, a21);
        float2 f; f.x = a11; f.y = a21; T2D[(rr+1)*HID + 64+L] = f;
      }
    }
#pragma unroll 6
    for (int rr = 0; rr < 36; ++rr){
      int   kp = __builtin_amdgcn_readlane(kpB, rr);
      float cu = __int_as_float(__builtin_amdgcn_readlane(__float_as_int(cuB), rr));
      float cv = __int_as_float(__builtin_amdgcn_readlane(__float_as_int(cvB), rr));
      int k = kp & 127;
      float w0 = W2[k*HID + L];
      a10 = fmaf(cu, w0, a10); a20 = fmaf(cv, w0, a20);
      { float2 f; f.x = a10; f.y = a20; T2D[(65+rr)*HID + L] = f; }
      if (L < 36){
        float w1 = W2[k*HID + 64+L];
        a11 = fmaf(cu, w1, a11); a21 = fmaf(cv, w1, a21);
        float2 f; f.x = a11; f.y = a21; T2D[(65+rr)*HID + 64+L] = f;
      }
    }
  }
  __syncthreads();   // table + angles0 visible

  // ---------- CEM loop: 99 evaluations ----------
#pragma unroll 1
  for (int t = 0; t < 99; ++t){
    // --- G: q_c = sum_n relu(T1[r][n] + a*T2[r][n]) * W3[n] ---
    if (gact){
      const float av = AQ[gc];            // LDS broadcast (8 lanes same addr)
      int rk = 0;
#pragma unroll
      for (int i = 0; i < 13; ++i) rk += (st_r[i] < av) ? 1 : 0;
      rk += DPPI(rk, 0xB1);
      rk += DPPI(rk, 0x4E);
      rk += iswap4(rk);
      const float2* __restrict__ Trow = T2D + rk*HID;
      float acc = 0.0f;
#pragma unroll
      for (int i = 0; i < 13; ++i){
        int n = gj + (i<<3);
        n = (n < HID) ? n : gj;           // clamp (w3r=0 there; avoids inf*0)
        float2 tv = Trow[n];
        float h = fmaxf(fmaf(av, tv.y, tv.x), 0.0f);
        acc = fmaf(h, w3r[i], acc);
      }
      acc = DPPADD(acc, 0xB1);
      acc = DPPADD(acc, 0x4E);
      acc += fswap4(acc);
      if (gj == 0) AQ[gc] = acc;          // q overwrites a (own group's slot;
                                          // wave-lockstep: read av precedes)
    }
    // --- eps(t+1) on wave7 (keys in registers, 1 threefry + erfinv) ---
    if (wv == 7 && t < 98 && lane < MCAND){
      uint32_t gidx = (uint32_t)b*MCAND + (uint32_t)lane;
      uint32_t r0, r1, bits;
      if (gidx < 102400u){ tf2x32(kk0,kk1,gidx,gidx+102400u,r0,r1); bits = r0; }
      else               { tf2x32(kk0,kk1,gidx-102400u,gidx,r0,r1); bits = r1; }
      float fl = __uint_as_float((bits>>9) | 0x3f800000u) - 1.0f;
      float u  = fmaxf(MINVC, fl*2.0f + MINVC);
      EPB[lane] = SQRT2C * erfinv32(u);
    }
    __syncthreads();   // B1: q(t) + eps(t+1) visible

    // --- S: wave0 stats; wave7 computes kk(t+1) (hidden) ---
    if (wv == 0){
      float q = (lane < MCAND) ? (AQ[lane] + sB3v) : -INFINITY;
      // sort 32-halves in opposite directions, j=32 max-merge -> top-32 multiset
      float v = q;
#define BST(KK, JJ, PV) { float pv = (PV); bool lower = (lane & (JJ)) == 0; \
        bool asc = (lane & (KK)) != 0; float mn = fminf(v, pv), mx = fmaxf(v, pv); \
        v = (lower == asc) ? mn : mx; }
      BST(2, 1,  DPPF(v, 0xB1))
      BST(4, 2,  DPPF(v, 0x4E))
      BST(4, 1,  DPPF(v, 0xB1))
      BST(8, 4,  fswap4(v))
      BST(8, 2,  DPPF(v, 0x4E))
      BST(8, 1,  DPPF(v, 0xB1))
      BST(16, 8, fswap8(v))
      BST(16, 4, fswap4(v))
      BST(16, 2, DPPF(v, 0x4E))
      BST(16, 1, DPPF(v, 0xB1))
      BST(32, 16, fswap16(v))
      BST(32, 8,  fswap8(v))
      BST(32, 4,  fswap4(v))
      BST(32, 2,  DPPF(v, 0x4E))
      BST(32, 1,  DPPF(v, 0xB1))
#undef BST
      {
        float pv = fswap32(v);
        v = ((lane & 32) == 0) ? fmaxf(v, pv) : fminf(v, pv);
      }
      // sum / sum-of-squares over lanes 0..31 (same add order as r2/r3/r6)
      float sv = (lane < NTOP) ? v : 0.0f;
      sv += fswap32(sv);
      sv += fswap16(sv);
      sv += fswap8(sv);
      sv += fswap4(sv);
      sv = DPPADD(sv, 0x4E);
      sv = DPPADD(sv, 0xB1);
      float mun = sv / 32.0f;
      float dv = (lane < NTOP) ? (v - mun) : 0.0f;
      float s2 = dv*dv;
      s2 += fswap32(s2);
      s2 += fswap16(s2);
      s2 += fswap8(s2);
      s2 += fswap4(s2);
      s2 = DPPADD(s2, 0x4E);
      s2 = DPPADD(s2, 0xB1);
      float stdv = sqrtf(s2 / 31.0f);
      if (t == 98){
        if (lane == 0) out[b] = mun * 6.2831854820251465f;  // fp32(2*pi)
      } else if (lane < MCAND){
        AQ[lane] = fmaf(stdv, EPB[lane], mun);              // a(t+1)
      }
    } else if (wv == 7 && t < 98){
      // keys for t+1 (redundant per lane; wave7 is idle in S otherwise)
      uint32_t nt = (uint32_t)(t + 1);
      { uint32_t i0 = 2u*nt;      uint32_t ii = (i0 < 99u) ? i0 : (i0 - 99u);
        uint32_t x,y; tf2x32(A1k,B1k, ii, 99u+ii, x, y); kk0 = (i0 < 99u) ? x : y; }
      { uint32_t i1 = 2u*nt + 1u; uint32_t ii = (i1 < 99u) ? i1 : (i1 - 99u);
        uint32_t x,y; tf2x32(A1k,B1k, ii, 99u+ii, x, y); kk1 = (i1 < 99u) ? x : y; }
    }
    __syncthreads();   // B2: a(t+1) visible
  }
}

extern "C" void kernel_launch(void* const* d_in, const int* in_sizes, int n_in,
                              void* d_out, int out_size, void* d_ws, size_t ws_size,
                              hipStream_t stream) {
  const float* states = (const float*)d_in[0];
  const float* W1     = (const float*)d_in[1];
  const float* b1     = (const float*)d_in[2];
  const float* W2     = (const float*)d_in[3];
  const float* b2     = (const float*)d_in[4];
  const float* W3     = (const float*)d_in[5];
  const float* b3     = (const float*)d_in[6];
  float* out = (float*)d_out;
  hipLaunchKernelGGL(cem_kernel, dim3(BATCH), dim3(512), 0, stream,
                     states, W1, b1, W2, b2, W3, b3, out);
}

// Round 8
// 1315.971 us; speedup vs baseline: 1.1341x; 1.0513x over previous
//
#include <hip/hip_runtime.h>
#include <math.h>
#include <stdint.h>

#define BATCH 4096
#define MCAND 50
#define NTOP 32
#define HID 100
#define TFL 20200                  /* floats per (T1,T2) table: 101*100*2 */
#define EPS_ROWS 98
#define EPS_ROWSZ (BATCH*MCAND)              /* 204800 */
#define WS_NEED   (1024u + (size_t)EPS_ROWS*EPS_ROWSZ*4u)

#define MINVC  (-0x1.fffffep-1f)   /* nextafter(-1,0) */
#define SQRT2C (0x1.6a09e6p+0f)    /* fp32 sqrt(2) */

__device__ __forceinline__ uint32_t rotl32(uint32_t v, int d){ return (v<<d)|(v>>(32-d)); }

// JAX threefry2x32 core (20 rounds, 5 key injections)
__device__ __forceinline__ void tf2x32(uint32_t k0, uint32_t k1, uint32_t x0, uint32_t x1,
                                       uint32_t &o0, uint32_t &o1){
  uint32_t k2 = k0 ^ k1 ^ 0x1BD11BDAu;
  x0 += k0; x1 += k1;
#define RND(r) { x0 += x1; x1 = rotl32(x1,(r)); x1 ^= x0; }
  RND(13) RND(15) RND(26) RND(6)
  x0 += k1; x1 += k2 + 1u;
  RND(17) RND(29) RND(16) RND(24)
  x0 += k2; x1 += k0 + 2u;
  RND(13) RND(15) RND(26) RND(6)
  x0 += k0; x1 += k1 + 3u;
  RND(17) RND(29) RND(16) RND(24)
  x0 += k1; x1 += k2 + 4u;
  RND(13) RND(15) RND(26) RND(6)
  x0 += k2; x1 += k0 + 5u;
#undef RND
  o0 = x0; o1 = x1;
}

// XLA ErfInv32 (Giles). w = -log1p(-x*x)
__device__ __forceinline__ float erfinv32(float x){
  float w = -log1pf(-x*x);
  float p;
  if (w < 5.0f){
    w = w - 2.5f;
    p = 2.81022636e-08f;
    p = fmaf(p, w, 3.43273939e-07f);
    p = fmaf(p, w, -3.5233877e-06f);
    p = fmaf(p, w, -4.39150654e-06f);
    p = fmaf(p, w, 0.00021858087f);
    p = fmaf(p, w, -0.00125372503f);
    p = fmaf(p, w, -0.00417768164f);
    p = fmaf(p, w, 0.246640727f);
    p = fmaf(p, w, 1.50140941f);
  } else {
    w = sqrtf(w) - 3.0f;
    p = -0.000200214257f;
    p = fmaf(p, w, 0.000100950558f);
    p = fmaf(p, w, 0.00134934322f);
    p = fmaf(p, w, -0.00367342844f);
    p = fmaf(p, w, 0.00573950773f);
    p = fmaf(p, w, -0.0076224613f);
    p = fmaf(p, w, 0.00943887047f);
    p = fmaf(p, w, 1.00167406f);
    p = fmaf(p, w, 2.83297682f);
  }
  return p*x;
}

// ---- VALU-only lane exchanges (no DS pipe) ----
#define DPPF(v, CTRL) __int_as_float(__builtin_amdgcn_update_dpp( \
    0, __float_as_int(v), (CTRL), 0xF, 0xF, true))
#define DPPI(v, CTRL) __builtin_amdgcn_update_dpp(0, (v), (CTRL), 0xF, 0xF, true)
#define DPPADD(v, CTRL) ((v) + DPPF((v), (CTRL)))

__device__ __forceinline__ float fswap4(float v){        // v[lane^4]
  float a = DPPF(v, 0x114);   // row_shr:4
  float b = DPPF(v, 0x104);   // row_shl:4
  return (threadIdx.x & 4) ? a : b;
}
__device__ __forceinline__ int iswap4(int v){
  int a = DPPI(v, 0x114), b = DPPI(v, 0x104);
  return (threadIdx.x & 4) ? a : b;
}
__device__ __forceinline__ float fswap8(float v){        // v[lane^8] = row_ror:8
  return DPPF(v, 0x128);
}
__device__ __forceinline__ float fswap16(float v){       // v[lane^16]
#if __has_builtin(__builtin_amdgcn_permlane16_swap)
  auto r = __builtin_amdgcn_permlane16_swap(__float_as_uint(v), __float_as_uint(v), false, false);
  return __uint_as_float((threadIdx.x & 16) ? r[0] : r[1]);
#else
  return __shfl_xor(v, 16, 64);
#endif
}
__device__ __forceinline__ float fswap32(float v){       // v[lane^32]
#if __has_builtin(__builtin_amdgcn_permlane32_swap)
  auto r = __builtin_amdgcn_permlane32_swap(__float_as_uint(v), __float_as_uint(v), false, false);
  return __uint_as_float((threadIdx.x & 32) ? r[0] : r[1]);
#else
  return __shfl_xor(v, 32, 64);
#endif
}

// ---------------------------------------------------------------------------
// Pre-kernels (r3 approach, improved): one thread produces TWO eps values
// (threefry yields r0 for element g, r1 for g+102400) -> half the RNG work.
// Layout [t][g] (g = b*50+c): in-loop row load is 50 contiguous floats.
// ---------------------------------------------------------------------------
__global__ void keys_kernel(uint32_t* __restrict__ K){
  int tid = threadIdx.x;
  if (tid < 99){
    uint32_t A0, B0, A1, B1;
    tf2x32(0u,42u,0u,2u,A0,A1);
    tf2x32(0u,42u,1u,3u,B0,B1);
    (void)A0; (void)B0;
    uint32_t o0,o1;
    tf2x32(A1,B1,(uint32_t)tid,(uint32_t)(99+tid),o0,o1);
    K[tid]    = o0;
    K[99+tid] = o1;
  }
}

__device__ __forceinline__ float bits2norm(uint32_t bits){
  float fl = __uint_as_float((bits>>9) | 0x3f800000u) - 1.0f;
  float u  = fmaxf(MINVC, fl*2.0f + MINVC);
  return SQRT2C * erfinv32(u);
}

__global__ __launch_bounds__(256) void eps_kernel(const uint32_t* __restrict__ K,
                                                  float* __restrict__ E){
  int id = blockIdx.x*256 + threadIdx.x;     // 98 * 102400 threads
  int t  = id / 102400;
  int g  = id - t*102400;
  uint32_t kk0 = K[2*t], kk1 = K[2*t+1];
  uint32_t r0, r1;
  tf2x32(kk0,kk1,(uint32_t)g,(uint32_t)g+102400u,r0,r1);
  // element g uses r0 (x0=g,x1=g+102400); element g+102400 uses r1 (same ctr)
  E[(size_t)t*EPS_ROWSZ + g]           = bits2norm(r0);
  E[(size_t)t*EPS_ROWSZ + g + 102400]  = bits2norm(r1);
}

// ---------------------------------------------------------------------------
// Piecewise-linear CEM — r7 structure with (1) eps restored to a parallel
// pre-kernel (r7 proved in-loop RNG costs ~240us of issue; the global load
// was never the stall) and (2) the gather stripped to stride-uniform
// addressing: one byte-base + 12 ds_read_b64 with IMMEDIATE offsets + one
// exec-masked tail read (gj<4). Numerically identical to r7 (the old clamp
// added h*0 = +0 in the same slot).
// Loop (2 barriers):
//   G: waves 0-6 gather q(t); wave7 stages eps row t (global->LDS, hidden).
//   B1;  S: wave0 top-32 mu/std (VALU bitonic) -> AQ[] = a(t+1);  B2.
// LDS: table 20,200 + AQ 50 + EPB 50 = 81,200 B -> 2 blocks/CU.
// ---------------------------------------------------------------------------
template<bool EPSG>
__global__ __launch_bounds__(512) void cem_kernel(
    const float* __restrict__ states, const float* __restrict__ W1,
    const float* __restrict__ b1,     const float* __restrict__ W2,
    const float* __restrict__ b2,     const float* __restrict__ W3,
    const float* __restrict__ b3,     const float* __restrict__ epsg,
    float* __restrict__ out)
{
  __shared__ __align__(16) float smem[20300];           // 81,200 B
  float*  const Tb   = smem;                            // table region
  float2* const T2D  = (float2*)Tb;                     // [101][100] (T1,T2)
  int*    const ORD  = (int*)(Tb + 300);                // init scratch (in T)
  float*  const STm  = Tb + 400;                        // init scratch (in T)
  float*  const AQ   = smem + 20200;                    // [50] angles <-> q
  float*  const EPB  = smem + 20250;                    // [50] eps

  const int tid  = threadIdx.x;
  const int b    = blockIdx.x;
  const int wv   = tid >> 6;
  const int lane = tid & 63;
  const int gc   = tid >> 3;            // gather candidate (8 lanes/cand)
  const int gj   = tid & 7;
  const bool gact = (tid < 8*MCAND);    // tid < 400 (waves 0-6)

  // per-thread W3 slice for the gather (n = gj + 8i)
  float w3r[13];
#pragma unroll
  for (int i = 0; i < 13; ++i){
    int n = gj + (i<<3);
    w3r[i] = (n < HID) ? W3[n] : 0.0f;
  }
  const float sB3v = b3[0];

  // fallback-path wave7 register state
  uint32_t A1k = 0u, B1k = 0u, kk0 = 0u, kk1 = 0u;

  // ---------- init P0: u,v,thresholds; angles0; (fallback) key state ----------
  if (tid < HID){
    float u = fmaf(states[2*b], W1[tid], fmaf(states[2*b+1], W1[HID+tid], b1[tid]));
    float v = W1[2*HID+tid];
    float tt = (v != 0.0f) ? (-u / v) : INFINITY;
    Tb[tid]     = u;
    Tb[HID+tid] = v;
    Tb[200+tid] = tt;
  }
  if (tid >= 128 && tid < 128 + MCAND){
    // iteration-0 uniform angles (mu=0, std=1)
    int c = tid - 128;
    uint32_t A0, B0, a1t, b1t;
    tf2x32(0u,42u,0u,2u,A0,a1t);
    tf2x32(0u,42u,1u,3u,B0,b1t);
    uint32_t gidx = (uint32_t)b*MCAND + (uint32_t)c;
    uint32_t r0,r1,bits;
    if (gidx < 102400u){ tf2x32(A0,B0,gidx,gidx+102400u,r0,r1); bits = r0; }
    else               { tf2x32(A0,B0,gidx-102400u,gidx,r0,r1); bits = r1; }
    AQ[c] = __uint_as_float((bits>>9) | 0x3f800000u) - 1.0f;
  }
  if (!EPSG && wv == 7){
    uint32_t A0, B0;
    tf2x32(0u,42u,0u,2u,A0,A1k);
    tf2x32(0u,42u,1u,3u,B0,B1k);
    { uint32_t i0 = 0u; uint32_t x,y; tf2x32(A1k,B1k, i0, 99u+i0, x, y); kk0 = x; }
    { uint32_t i1 = 1u; uint32_t x,y; tf2x32(A1k,B1k, i1, 99u+i1, x, y); kk1 = x; }
  }
  __syncthreads();

  // ---------- init P1: stable rank-by-count, scatter sorted ----------
  if (tid < HID){
    float tk = Tb[200+tid];
    int rk = 0;
    for (int j2 = 0; j2 < HID; ++j2){
      float tj = Tb[200+j2];
      rk += (tj < tk || (tj == tk && j2 < tid)) ? 1 : 0;
    }
    float u = Tb[tid], v = Tb[HID+tid];
    // neg-type: active iff a < t (v<0, or v==0 with u>0 -> always active, t=+inf)
    int neg = (v < 0.0f || (v == 0.0f && u > 0.0f)) ? 1 : 0;
    STm[rk] = tk;
    ORD[rk] = tid | (neg << 7);
  }
  __syncthreads();

  // ---------- init P1.5: builder meta -> regs (wave0); thresholds -> regs ----------
  int kpA = 0, kpB = 0; float cuA = 0.f, cvA = 0.f, cuB = 0.f, cvB = 0.f;
  if (wv == 0){
    kpA = ORD[lane];
    int kiA = kpA & 127;
    float uA = Tb[kiA], vA = Tb[HID+kiA];
    cuA = (kpA & 128) ? -uA : uA;     // signed delta for prefix pass
    cvA = (kpA & 128) ? -vA : vA;
    if (lane < 36){
      kpB = ORD[64+lane];
      int kiB = kpB & 127;
      float uB = Tb[kiB], vB = Tb[HID+kiB];
      cuB = (kpB & 128) ? -uB : uB;
      cvB = (kpB & 128) ? -vB : vB;
    }
  }
  float st_r[13];                       // loop-invariant thresholds in regs
#pragma unroll
  for (int i = 0; i < 13; ++i){
    int idx = gj*13 + i;
    st_r[i] = (idx < HID) ? STm[idx] : INFINITY;
  }
  __syncthreads();   // meta/thresholds consumed; T scratch region now dead

  // ---------- init P2: wave0 builds the 101-row prefix table ----------
  if (wv == 0){
    const int L = lane;          // columns n=L and n=64+L (L<36)
    float a10 = b2[L], a20 = 0.0f;
    float a11 = (L < 36) ? b2[64+L] : 0.0f, a21 = 0.0f;
    // pass 1: rank-0 base = b2 + sum over neg-type features of (+u,+v)*W2row
#pragma unroll 8
    for (int rr = 0; rr < 64; ++rr){
      int   kp = __builtin_amdgcn_readlane(kpA, rr);
      float cu = __int_as_float(__builtin_amdgcn_readlane(__float_as_int(cuA), rr));
      float cv = __int_as_float(__builtin_amdgcn_readlane(__float_as_int(cvA), rr));
      int k = kp & 127;
      float bu = (kp & 128) ? -cu : 0.0f;  // = +u for neg-type, 0 for pos-type
      float bv = (kp & 128) ? -cv : 0.0f;
      float w0 = W2[k*HID + L];
      a10 = fmaf(bu, w0, a10); a20 = fmaf(bv, w0, a20);
      if (L < 36){
        float w1 = W2[k*HID + 64+L];
        a11 = fmaf(bu, w1, a11); a21 = fmaf(bv, w1, a21);
      }
    }
#pragma unroll 6
    for (int rr = 0; rr < 36; ++rr){
      int   kp = __builtin_amdgcn_readlane(kpB, rr);
      float cu = __int_as_float(__builtin_amdgcn_readlane(__float_as_int(cuB), rr));
      float cv = __int_as_float(__builtin_amdgcn_readlane(__float_as_int(cvB), rr));
      int k = kp & 127;
      float bu = (kp & 128) ? -cu : 0.0f;
      float bv = (kp & 128) ? -cv : 0.0f;
      float w0 = W2[k*HID + L];
      a10 = fmaf(bu, w0, a10); a20 = fmaf(bv, w0, a20);
      if (L < 36){
        float w1 = W2[k*HID + 64+L];
        a11 = fmaf(bu, w1, a11); a21 = fmaf(bv, w1, a21);
      }
    }
    { float2 f; f.x = a10; f.y = a20; T2D[L] = f; }
    if (L < 36){ float2 f; f.x = a11; f.y = a21; T2D[64+L] = f; }
    // pass 2: ascending ranks, signed deltas, write T[rr+1]
#pragma unroll 8
    for (int rr = 0; rr < 64; ++rr){
      int   kp = __builtin_amdgcn_readlane(kpA, rr);
      float cu = __int_as_float(__builtin_amdgcn_readlane(__float_as_int(cuA), rr));
      float cv = __int_as_float(__builtin_amdgcn_readlane(__float_as_int(cvA), rr));
      int k = kp & 127;
      float w0 = W2[k*HID + L];
      a10 = fmaf(cu, w0, a10); a20 = fmaf(cv, w0, a20);
      { float2 f; f.x = a10; f.y = a20; T2D[(rr+1)*HID + L] = f; }
      if (L < 36){
        float w1 = W2[k*HID + 64+L];
        a11 = fmaf(cu, w1, a11); a21 = fmaf(cv, w1, a21);
        float2 f; f.x = a11; f.y = a21; T2D[(rr+1)*HID + 64+L] = f;
      }
    }
#pragma unroll 6
    for (int rr = 0; rr < 36; ++rr){
      int   kp = __builtin_amdgcn_readlane(kpB, rr);
      float cu = __int_as_float(__builtin_amdgcn_readlane(__float_as_int(cuB), rr));
      float cv = __int_as_float(__builtin_amdgcn_readlane(__float_as_int(cvB), rr));
      int k = kp & 127;
      float w0 = W2[k*HID + L];
      a10 = fmaf(cu, w0, a10); a20 = fmaf(cv, w0, a20);
      { float2 f; f.x = a10; f.y = a20; T2D[(65+rr)*HID + L] = f; }
      if (L < 36){
        float w1 = W2[k*HID + 64+L];
        a11 = fmaf(cu, w1, a11); a21 = fmaf(cv, w1, a21);
        float2 f; f.x = a11; f.y = a21; T2D[(65+rr)*HID + 64+L] = f;
      }
    }
  }
  __syncthreads();   // table + angles0 visible

  // ---------- CEM loop: 99 evaluations ----------
#pragma unroll 1
  for (int t = 0; t < 99; ++t){
    // --- G: q_c = sum_n relu(T1[r][n] + a*T2[r][n]) * W3[n] ---
    if (gact){
      const float av = AQ[gc];            // LDS broadcast (8 lanes same addr)
      int rk = 0;
#pragma unroll
      for (int i = 0; i < 13; ++i) rk += (st_r[i] < av) ? 1 : 0;
      rk += DPPI(rk, 0xB1);
      rk += DPPI(rk, 0x4E);
      rk += iswap4(rk);
      // stride-uniform addressing: byte base once, 12 imm-offset b64 reads
      const char* rowp = (const char*)T2D + (((rk*HID) + gj) << 3);
      float acc = 0.0f;
#pragma unroll
      for (int i = 0; i < 12; ++i){
        float2 tv = *(const float2*)(rowp + (i << 6));   // n = gj + 8i
        float h = fmaxf(fmaf(av, tv.y, tv.x), 0.0f);
        acc = fmaf(h, w3r[i], acc);
      }
      if (gj < 4){                        // tail n = 96+gj (others added +0)
        float2 tv = *(const float2*)(rowp + (12 << 6));
        float h = fmaxf(fmaf(av, tv.y, tv.x), 0.0f);
        acc = fmaf(h, w3r[12], acc);
      }
      acc = DPPADD(acc, 0xB1);
      acc = DPPADD(acc, 0x4E);
      acc += fswap4(acc);
      if (gj == 0) AQ[gc] = acc;          // q overwrites a (own group's slot)
    }
    // --- eps(t+1): wave7 stages row t (EPSG) or computes it (fallback) ---
    if (EPSG){
      if (wv == 7 && t < EPS_ROWS && lane < MCAND)
        EPB[lane] = epsg[(size_t)t*EPS_ROWSZ + (size_t)b*MCAND + (size_t)lane];
    } else if (wv == 7 && t < EPS_ROWS && lane < MCAND){
      uint32_t gidx = (uint32_t)b*MCAND + (uint32_t)lane;
      uint32_t r0, r1, bits;
      if (gidx < 102400u){ tf2x32(kk0,kk1,gidx,gidx+102400u,r0,r1); bits = r0; }
      else               { tf2x32(kk0,kk1,gidx-102400u,gidx,r0,r1); bits = r1; }
      EPB[lane] = bits2norm(bits);
    }
    __syncthreads();   // B1: q(t) + eps row visible

    // --- S: wave0 stats; (fallback) wave7 computes kk(t+1) ---
    if (wv == 0){
      float q = (lane < MCAND) ? (AQ[lane] + sB3v) : -INFINITY;
      // sort 32-halves in opposite directions, j=32 max-merge -> top-32 multiset
      float v = q;
#define BST(KK, JJ, PV) { float pv = (PV); bool lower = (lane & (JJ)) == 0; \
        bool asc = (lane & (KK)) != 0; float mn = fminf(v, pv), mx = fmaxf(v, pv); \
        v = (lower == asc) ? mn : mx; }
      BST(2, 1,  DPPF(v, 0xB1))
      BST(4, 2,  DPPF(v, 0x4E))
      BST(4, 1,  DPPF(v, 0xB1))
      BST(8, 4,  fswap4(v))
      BST(8, 2,  DPPF(v, 0x4E))
      BST(8, 1,  DPPF(v, 0xB1))
      BST(16, 8, fswap8(v))
      BST(16, 4, fswap4(v))
      BST(16, 2, DPPF(v, 0x4E))
      BST(16, 1, DPPF(v, 0xB1))
      BST(32, 16, fswap16(v))
      BST(32, 8,  fswap8(v))
      BST(32, 4,  fswap4(v))
      BST(32, 2,  DPPF(v, 0x4E))
      BST(32, 1,  DPPF(v, 0xB1))
#undef BST
      {
        float pv = fswap32(v);
        v = ((lane & 32) == 0) ? fmaxf(v, pv) : fminf(v, pv);
      }
      // sum / sum-of-squares over lanes 0..31 (same add order as r2..r7)
      float sv = (lane < NTOP) ? v : 0.0f;
      sv += fswap32(sv);
      sv += fswap16(sv);
      sv += fswap8(sv);
      sv += fswap4(sv);
      sv = DPPADD(sv, 0x4E);
      sv = DPPADD(sv, 0xB1);
      float mun = sv / 32.0f;
      float dv = (lane < NTOP) ? (v - mun) : 0.0f;
      float s2 = dv*dv;
      s2 += fswap32(s2);
      s2 += fswap16(s2);
      s2 += fswap8(s2);
      s2 += fswap4(s2);
      s2 = DPPADD(s2, 0x4E);
      s2 = DPPADD(s2, 0xB1);
      float stdv = sqrtf(s2 / 31.0f);
      if (t == 98){
        if (lane == 0) out[b] = mun * 6.2831854820251465f;  // fp32(2*pi)
      } else if (lane < MCAND){
        AQ[lane] = fmaf(stdv, EPB[lane], mun);              // a(t+1)
      }
    } else if (!EPSG && wv == 7 && t < EPS_ROWS){
      uint32_t nt = (uint32_t)(t + 1);
      { uint32_t i0 = 2u*nt;      uint32_t ii = (i0 < 99u) ? i0 : (i0 - 99u);
        uint32_t x,y; tf2x32(A1k,B1k, ii, 99u+ii, x, y); kk0 = (i0 < 99u) ? x : y; }
      { uint32_t i1 = 2u*nt + 1u; uint32_t ii = (i1 < 99u) ? i1 : (i1 - 99u);
        uint32_t x,y; tf2x32(A1k,B1k, ii, 99u+ii, x, y); kk1 = (i1 < 99u) ? x : y; }
    }
    __syncthreads();   // B2: a(t+1) visible
  }
}

extern "C" void kernel_launch(void* const* d_in, const int* in_sizes, int n_in,
                              void* d_out, int out_size, void* d_ws, size_t ws_size,
                              hipStream_t stream) {
  const float* states = (const float*)d_in[0];
  const float* W1     = (const float*)d_in[1];
  const float* b1     = (const float*)d_in[2];
  const float* W2     = (const float*)d_in[3];
  const float* b2     = (const float*)d_in[4];
  const float* W3     = (const float*)d_in[5];
  const float* b3     = (const float*)d_in[6];
  float* out = (float*)d_out;

  if (d_ws != nullptr && ws_size >= WS_NEED){
    uint32_t* K = (uint32_t*)d_ws;
    float*    E = (float*)((char*)d_ws + 1024);
    hipLaunchKernelGGL(keys_kernel, dim3(1), dim3(128), 0, stream, K);
    hipLaunchKernelGGL(eps_kernel, dim3(EPS_ROWS*102400/256), dim3(256), 0, stream, K, E);
    hipLaunchKernelGGL(HIP_KERNEL_NAME(cem_kernel<true>), dim3(BATCH), dim3(512), 0, stream,
                       states, W1, b1, W2, b2, W3, b3, (const float*)E, out);
  } else {
    hipLaunchKernelGGL(HIP_KERNEL_NAME(cem_kernel<false>), dim3(BATCH), dim3(512), 0, stream,
                       states, W1, b1, W2, b2, W3, b3, (const float*)nullptr, out);
  }
}

// Round 9
// 1312.651 us; speedup vs baseline: 1.1370x; 1.0025x over previous
//
#include <hip/hip_runtime.h>
#include <math.h>
#include <stdint.h>

#define BATCH 4096
#define MCAND 50
#define NTOP 32
#define HID 100
#define TFL 20200                  /* floats per (T1,T2) table: 101*100*2 */
#define EPS_ROWS 98
#define EPS_ROWSZ (BATCH*MCAND)              /* 204800 */
#define WS_NEED   (1024u + (size_t)EPS_ROWS*EPS_ROWSZ*4u)

#define MINVC  (-0x1.fffffep-1f)   /* nextafter(-1,0) */
#define SQRT2C (0x1.6a09e6p+0f)    /* fp32 sqrt(2) */

__device__ __forceinline__ uint32_t rotl32(uint32_t v, int d){ return (v<<d)|(v>>(32-d)); }

// JAX threefry2x32 core (20 rounds, 5 key injections)
__device__ __forceinline__ void tf2x32(uint32_t k0, uint32_t k1, uint32_t x0, uint32_t x1,
                                       uint32_t &o0, uint32_t &o1){
  uint32_t k2 = k0 ^ k1 ^ 0x1BD11BDAu;
  x0 += k0; x1 += k1;
#define RND(r) { x0 += x1; x1 = rotl32(x1,(r)); x1 ^= x0; }
  RND(13) RND(15) RND(26) RND(6)
  x0 += k1; x1 += k2 + 1u;
  RND(17) RND(29) RND(16) RND(24)
  x0 += k2; x1 += k0 + 2u;
  RND(13) RND(15) RND(26) RND(6)
  x0 += k0; x1 += k1 + 3u;
  RND(17) RND(29) RND(16) RND(24)
  x0 += k1; x1 += k2 + 4u;
  RND(13) RND(15) RND(26) RND(6)
  x0 += k2; x1 += k0 + 5u;
#undef RND
  o0 = x0; o1 = x1;
}

// XLA ErfInv32 (Giles). w = -log1p(-x*x)
__device__ __forceinline__ float erfinv32(float x){
  float w = -log1pf(-x*x);
  float p;
  if (w < 5.0f){
    w = w - 2.5f;
    p = 2.81022636e-08f;
    p = fmaf(p, w, 3.43273939e-07f);
    p = fmaf(p, w, -3.5233877e-06f);
    p = fmaf(p, w, -4.39150654e-06f);
    p = fmaf(p, w, 0.00021858087f);
    p = fmaf(p, w, -0.00125372503f);
    p = fmaf(p, w, -0.00417768164f);
    p = fmaf(p, w, 0.246640727f);
    p = fmaf(p, w, 1.50140941f);
  } else {
    w = sqrtf(w) - 3.0f;
    p = -0.000200214257f;
    p = fmaf(p, w, 0.000100950558f);
    p = fmaf(p, w, 0.00134934322f);
    p = fmaf(p, w, -0.00367342844f);
    p = fmaf(p, w, 0.00573950773f);
    p = fmaf(p, w, -0.0076224613f);
    p = fmaf(p, w, 0.00943887047f);
    p = fmaf(p, w, 1.00167406f);
    p = fmaf(p, w, 2.83297682f);
  }
  return p*x;
}

// ---- VALU-only lane exchanges (no DS pipe) ----
#define DPPF(v, CTRL) __int_as_float(__builtin_amdgcn_update_dpp( \
    0, __float_as_int(v), (CTRL), 0xF, 0xF, true))
#define DPPI(v, CTRL) __builtin_amdgcn_update_dpp(0, (v), (CTRL), 0xF, 0xF, true)
#define DPPADD(v, CTRL) ((v) + DPPF((v), (CTRL)))

__device__ __forceinline__ float fswap4(float v){        // v[lane^4]
  float a = DPPF(v, 0x114);   // row_shr:4
  float b = DPPF(v, 0x104);   // row_shl:4
  return (threadIdx.x & 4) ? a : b;
}
__device__ __forceinline__ int iswap4(int v){
  int a = DPPI(v, 0x114), b = DPPI(v, 0x104);
  return (threadIdx.x & 4) ? a : b;
}
__device__ __forceinline__ float fswap8(float v){        // v[lane^8] = row_ror:8
  return DPPF(v, 0x128);
}
__device__ __forceinline__ float fswap16(float v){       // v[lane^16]
#if __has_builtin(__builtin_amdgcn_permlane16_swap)
  auto r = __builtin_amdgcn_permlane16_swap(__float_as_uint(v), __float_as_uint(v), false, false);
  return __uint_as_float((threadIdx.x & 16) ? r[0] : r[1]);
#else
  return __shfl_xor(v, 16, 64);
#endif
}
__device__ __forceinline__ float fswap32(float v){       // v[lane^32]
#if __has_builtin(__builtin_amdgcn_permlane32_swap)
  auto r = __builtin_amdgcn_permlane32_swap(__float_as_uint(v), __float_as_uint(v), false, false);
  return __uint_as_float((threadIdx.x & 32) ? r[0] : r[1]);
#else
  return __shfl_xor(v, 32, 64);
#endif
}

// ---------------------------------------------------------------------------
// Pre-kernels (r8): one thread produces TWO eps values (threefry r0 -> g,
// r1 -> g+102400). Layout [t][g]; in-loop row load is 50 contiguous floats.
// ---------------------------------------------------------------------------
__global__ void keys_kernel(uint32_t* __restrict__ K){
  int tid = threadIdx.x;
  if (tid < 99){
    uint32_t A0, B0, A1, B1;
    tf2x32(0u,42u,0u,2u,A0,A1);
    tf2x32(0u,42u,1u,3u,B0,B1);
    (void)A0; (void)B0;
    uint32_t o0,o1;
    tf2x32(A1,B1,(uint32_t)tid,(uint32_t)(99+tid),o0,o1);
    K[tid]    = o0;
    K[99+tid] = o1;
  }
}

__device__ __forceinline__ float bits2norm(uint32_t bits){
  float fl = __uint_as_float((bits>>9) | 0x3f800000u) - 1.0f;
  float u  = fmaxf(MINVC, fl*2.0f + MINVC);
  return SQRT2C * erfinv32(u);
}

__global__ __launch_bounds__(256) void eps_kernel(const uint32_t* __restrict__ K,
                                                  float* __restrict__ E){
  int id = blockIdx.x*256 + threadIdx.x;     // 98 * 102400 threads
  int t  = id / 102400;
  int g  = id - t*102400;
  uint32_t kk0 = K[2*t], kk1 = K[2*t+1];
  uint32_t r0, r1;
  tf2x32(kk0,kk1,(uint32_t)g,(uint32_t)g+102400u,r0,r1);
  E[(size_t)t*EPS_ROWSZ + g]           = bits2norm(r0);
  E[(size_t)t*EPS_ROWSZ + g + 102400]  = bits2norm(r1);
}

// ---------------------------------------------------------------------------
// Piecewise-linear CEM — r8 with the eps row staged via SOFTWARE PREFETCH:
// wave7 carries `pref` (row t+1) in a register, loaded during G(t-1); at G(t)
// the vmcnt wait is already satisfied (one full iteration of slack), it
// writes EPB[(t+1)&1] and issues the row t+2 load with no wait. r3/r8 put
// the load and its consumption in the SAME iteration -> ~500cy of exposed
// HBM latency at B1 every iteration (the dominant stall; proven by r8's
// issue-cut having zero effect).
// Loop (2 barriers):
//   G: waves 0-6 gather q(t); wave7 {write pref -> EPB, issue next load}.
//   B1;  S: wave0 top-32 mu/std (VALU bitonic) -> AQ[] = a(t+1);  B2.
// LDS: table 20,200 + AQ 50 + EPB 2x50 = 81,400 B -> 2 blocks/CU.
// ---------------------------------------------------------------------------
template<bool EPSG>
__global__ __launch_bounds__(512) void cem_kernel(
    const float* __restrict__ states, const float* __restrict__ W1,
    const float* __restrict__ b1,     const float* __restrict__ W2,
    const float* __restrict__ b2,     const float* __restrict__ W3,
    const float* __restrict__ b3,     const float* __restrict__ epsg,
    float* __restrict__ out)
{
  __shared__ __align__(16) float smem[20350];           // 81,400 B
  float*  const Tb   = smem;                            // table region
  float2* const T2D  = (float2*)Tb;                     // [101][100] (T1,T2)
  int*    const ORD  = (int*)(Tb + 300);                // init scratch (in T)
  float*  const STm  = Tb + 400;                        // init scratch (in T)
  float*  const AQ   = smem + 20200;                    // [50] angles <-> q
  float*  const EPB  = smem + 20250;                    // [2][50] eps ping-pong

  const int tid  = threadIdx.x;
  const int b    = blockIdx.x;
  const int wv   = tid >> 6;
  const int lane = tid & 63;
  const int gc   = tid >> 3;            // gather candidate (8 lanes/cand)
  const int gj   = tid & 7;
  const bool gact = (tid < 8*MCAND);    // tid < 400 (waves 0-6)

  // per-thread W3 slice for the gather (n = gj + 8i)
  float w3r[13];
#pragma unroll
  for (int i = 0; i < 13; ++i){
    int n = gj + (i<<3);
    w3r[i] = (n < HID) ? W3[n] : 0.0f;
  }
  const float sB3v = b3[0];

  // fallback-path wave7 register state
  uint32_t A1k = 0u, B1k = 0u, kk0 = 0u, kk1 = 0u;

  // ---------- init P0: u,v,thresholds; angles0; (fallback) key state ----------
  if (tid < HID){
    float u = fmaf(states[2*b], W1[tid], fmaf(states[2*b+1], W1[HID+tid], b1[tid]));
    float v = W1[2*HID+tid];
    float tt = (v != 0.0f) ? (-u / v) : INFINITY;
    Tb[tid]     = u;
    Tb[HID+tid] = v;
    Tb[200+tid] = tt;
  }
  if (tid >= 128 && tid < 128 + MCAND){
    // iteration-0 uniform angles (mu=0, std=1)
    int c = tid - 128;
    uint32_t A0, B0, a1t, b1t;
    tf2x32(0u,42u,0u,2u,A0,a1t);
    tf2x32(0u,42u,1u,3u,B0,b1t);
    uint32_t gidx = (uint32_t)b*MCAND + (uint32_t)c;
    uint32_t r0,r1,bits;
    if (gidx < 102400u){ tf2x32(A0,B0,gidx,gidx+102400u,r0,r1); bits = r0; }
    else               { tf2x32(A0,B0,gidx-102400u,gidx,r0,r1); bits = r1; }
    AQ[c] = __uint_as_float((bits>>9) | 0x3f800000u) - 1.0f;
  }
  if (!EPSG && wv == 7){
    uint32_t A0, B0;
    tf2x32(0u,42u,0u,2u,A0,A1k);
    tf2x32(0u,42u,1u,3u,B0,B1k);
    { uint32_t i0 = 0u; uint32_t x,y; tf2x32(A1k,B1k, i0, 99u+i0, x, y); kk0 = x; }
    { uint32_t i1 = 1u; uint32_t x,y; tf2x32(A1k,B1k, i1, 99u+i1, x, y); kk1 = x; }
  }
  __syncthreads();

  // ---------- init P1: stable rank-by-count, scatter sorted ----------
  if (tid < HID){
    float tk = Tb[200+tid];
    int rk = 0;
    for (int j2 = 0; j2 < HID; ++j2){
      float tj = Tb[200+j2];
      rk += (tj < tk || (tj == tk && j2 < tid)) ? 1 : 0;
    }
    float u = Tb[tid], v = Tb[HID+tid];
    // neg-type: active iff a < t (v<0, or v==0 with u>0 -> always active, t=+inf)
    int neg = (v < 0.0f || (v == 0.0f && u > 0.0f)) ? 1 : 0;
    STm[rk] = tk;
    ORD[rk] = tid | (neg << 7);
  }
  __syncthreads();

  // ---------- init P1.5: builder meta -> regs (wave0); thresholds -> regs ----------
  int kpA = 0, kpB = 0; float cuA = 0.f, cvA = 0.f, cuB = 0.f, cvB = 0.f;
  if (wv == 0){
    kpA = ORD[lane];
    int kiA = kpA & 127;
    float uA = Tb[kiA], vA = Tb[HID+kiA];
    cuA = (kpA & 128) ? -uA : uA;     // signed delta for prefix pass
    cvA = (kpA & 128) ? -vA : vA;
    if (lane < 36){
      kpB = ORD[64+lane];
      int kiB = kpB & 127;
      float uB = Tb[kiB], vB = Tb[HID+kiB];
      cuB = (kpB & 128) ? -uB : uB;
      cvB = (kpB & 128) ? -vB : vB;
    }
  }
  float st_r[13];                       // loop-invariant thresholds in regs
#pragma unroll
  for (int i = 0; i < 13; ++i){
    int idx = gj*13 + i;
    st_r[i] = (idx < HID) ? STm[idx] : INFINITY;
  }
  __syncthreads();   // meta/thresholds consumed; T scratch region now dead

  // ---------- init P2: wave0 builds the 101-row prefix table ----------
  if (wv == 0){
    const int L = lane;          // columns n=L and n=64+L (L<36)
    float a10 = b2[L], a20 = 0.0f;
    float a11 = (L < 36) ? b2[64+L] : 0.0f, a21 = 0.0f;
    // pass 1: rank-0 base = b2 + sum over neg-type features of (+u,+v)*W2row
#pragma unroll 8
    for (int rr = 0; rr < 64; ++rr){
      int   kp = __builtin_amdgcn_readlane(kpA, rr);
      float cu = __int_as_float(__builtin_amdgcn_readlane(__float_as_int(cuA), rr));
      float cv = __int_as_float(__builtin_amdgcn_readlane(__float_as_int(cvA), rr));
      int k = kp & 127;
      float bu = (kp & 128) ? -cu : 0.0f;  // = +u for neg-type, 0 for pos-type
      float bv = (kp & 128) ? -cv : 0.0f;
      float w0 = W2[k*HID + L];
      a10 = fmaf(bu, w0, a10); a20 = fmaf(bv, w0, a20);
      if (L < 36){
        float w1 = W2[k*HID + 64+L];
        a11 = fmaf(bu, w1, a11); a21 = fmaf(bv, w1, a21);
      }
    }
#pragma unroll 6
    for (int rr = 0; rr < 36; ++rr){
      int   kp = __builtin_amdgcn_readlane(kpB, rr);
      float cu = __int_as_float(__builtin_amdgcn_readlane(__float_as_int(cuB), rr));
      float cv = __int_as_float(__builtin_amdgcn_readlane(__float_as_int(cvB), rr));
      int k = kp & 127;
      float bu = (kp & 128) ? -cu : 0.0f;
      float bv = (kp & 128) ? -cv : 0.0f;
      float w0 = W2[k*HID + L];
      a10 = fmaf(bu, w0, a10); a20 = fmaf(bv, w0, a20);
      if (L < 36){
        float w1 = W2[k*HID + 64+L];
        a11 = fmaf(bu, w1, a11); a21 = fmaf(bv, w1, a21);
      }
    }
    { float2 f; f.x = a10; f.y = a20; T2D[L] = f; }
    if (L < 36){ float2 f; f.x = a11; f.y = a21; T2D[64+L] = f; }
    // pass 2: ascending ranks, signed deltas, write T[rr+1]
#pragma unroll 8
    for (int rr = 0; rr < 64; ++rr){
      int   kp = __builtin_amdgcn_readlane(kpA, rr);
      float cu = __int_as_float(__builtin_amdgcn_readlane(__float_as_int(cuA), rr));
      float cv = __int_as_float(__builtin_amdgcn_readlane(__float_as_int(cvA), rr));
      int k = kp & 127;
      float w0 = W2[k*HID + L];
      a10 = fmaf(cu, w0, a10); a20 = fmaf(cv, w0, a20);
      { float2 f; f.x = a10; f.y = a20; T2D[(rr+1)*HID + L] = f; }
      if (L < 36){
        float w1 = W2[k*HID + 64+L];
        a11 = fmaf(cu, w1, a11); a21 = fmaf(cv, w1, a21);
        float2 f; f.x = a11; f.y = a21; T2D[(rr+1)*HID + 64+L] = f;
      }
    }
#pragma unroll 6
    for (int rr = 0; rr < 36; ++rr){
      int   kp = __builtin_amdgcn_readlane(kpB, rr);
      float cu = __int_as_float(__builtin_amdgcn_readlane(__float_as_int(cuB), rr));
      float cv = __int_as_float(__builtin_amdgcn_readlane(__float_as_int(cvB), rr));
      int k = kp & 127;
      float w0 = W2[k*HID + L];
      a10 = fmaf(cu, w0, a10); a20 = fmaf(cv, w0, a20);
      { float2 f; f.x = a10; f.y = a20; T2D[(65+rr)*HID + L] = f; }
      if (L < 36){
        float w1 = W2[k*HID + 64+L];
        a11 = fmaf(cu, w1, a11); a21 = fmaf(cv, w1, a21);
        float2 f; f.x = a11; f.y = a21; T2D[(65+rr)*HID + 64+L] = f;
      }
    }
  }

  // ---------- eps prefetch prologue (wave7, EPSG): row0 -> EPB[0]; issue row1 ----------
  float pref = 0.0f;
  if (EPSG && wv == 7 && lane < MCAND){
    const float* Eb = epsg + (size_t)b*MCAND + (size_t)lane;
    EPB[lane] = Eb[0];                         // row 0 (one-time synchronous)
    pref = Eb[(size_t)1*EPS_ROWSZ];            // row 1 issued; waited at t=0
  }
  __syncthreads();   // table + angles0 + eps row0 visible

  // ---------- CEM loop: 99 evaluations ----------
#pragma unroll 1
  for (int t = 0; t < 99; ++t){
    // --- G: q_c = sum_n relu(T1[r][n] + a*T2[r][n]) * W3[n] ---
    if (gact){
      const float av = AQ[gc];            // LDS broadcast (8 lanes same addr)
      int rk = 0;
#pragma unroll
      for (int i = 0; i < 13; ++i) rk += (st_r[i] < av) ? 1 : 0;
      rk += DPPI(rk, 0xB1);
      rk += DPPI(rk, 0x4E);
      rk += iswap4(rk);
      // stride-uniform addressing: byte base once, imm-offset b64 reads
      const char* rowp = (const char*)T2D + (((rk*HID) + gj) << 3);
      float acc = 0.0f;
#pragma unroll
      for (int i = 0; i < 12; ++i){
        float2 tv = *(const float2*)(rowp + (i << 6));   // n = gj + 8i
        float h = fmaxf(fmaf(av, tv.y, tv.x), 0.0f);
        acc = fmaf(h, w3r[i], acc);
      }
      if (gj < 4){                        // tail n = 96+gj (others added +0)
        float2 tv = *(const float2*)(rowp + (12 << 6));
        float h = fmaxf(fmaf(av, tv.y, tv.x), 0.0f);
        acc = fmaf(h, w3r[12], acc);
      }
      acc = DPPADD(acc, 0xB1);
      acc = DPPADD(acc, 0x4E);
      acc += fswap4(acc);
      if (gj == 0) AQ[gc] = acc;          // q overwrites a (own group's slot)
    }
    // --- eps staging: write prefetched row t+1, issue row t+2 (no wait) ---
    if (EPSG){
      if (wv == 7 && lane < MCAND && (t+1) < EPS_ROWS){
        EPB[((t+1)&1)*MCAND + lane] = pref;   // vmcnt wait: 1 full iter of slack
        if ((t+2) < EPS_ROWS)
          pref = epsg[(size_t)(t+2)*EPS_ROWSZ + (size_t)b*MCAND + (size_t)lane];
      }
    } else if (wv == 7 && t < EPS_ROWS && lane < MCAND){
      uint32_t gidx = (uint32_t)b*MCAND + (uint32_t)lane;
      uint32_t r0, r1, bits;
      if (gidx < 102400u){ tf2x32(kk0,kk1,gidx,gidx+102400u,r0,r1); bits = r0; }
      else               { tf2x32(kk0,kk1,gidx-102400u,gidx,r0,r1); bits = r1; }
      EPB[lane] = bits2norm(bits);
    }
    __syncthreads();   // B1: q(t) + eps row t visible

    // --- S: wave0 stats; (fallback) wave7 computes kk(t+1) ---
    if (wv == 0){
      float q = (lane < MCAND) ? (AQ[lane] + sB3v) : -INFINITY;
      // sort 32-halves in opposite directions, j=32 max-merge -> top-32 multiset
      float v = q;
#define BST(KK, JJ, PV) { float pv = (PV); bool lower = (lane & (JJ)) == 0; \
        bool asc = (lane & (KK)) != 0; float mn = fminf(v, pv), mx = fmaxf(v, pv); \
        v = (lower == asc) ? mn : mx; }
      BST(2, 1,  DPPF(v, 0xB1))
      BST(4, 2,  DPPF(v, 0x4E))
      BST(4, 1,  DPPF(v, 0xB1))
      BST(8, 4,  fswap4(v))
      BST(8, 2,  DPPF(v, 0x4E))
      BST(8, 1,  DPPF(v, 0xB1))
      BST(16, 8, fswap8(v))
      BST(16, 4, fswap4(v))
      BST(16, 2, DPPF(v, 0x4E))
      BST(16, 1, DPPF(v, 0xB1))
      BST(32, 16, fswap16(v))
      BST(32, 8,  fswap8(v))
      BST(32, 4,  fswap4(v))
      BST(32, 2,  DPPF(v, 0x4E))
      BST(32, 1,  DPPF(v, 0xB1))
#undef BST
      {
        float pv = fswap32(v);
        v = ((lane & 32) == 0) ? fmaxf(v, pv) : fminf(v, pv);
      }
      // sum / sum-of-squares over lanes 0..31 (same add order as r2..r8)
      float sv = (lane < NTOP) ? v : 0.0f;
      sv += fswap32(sv);
      sv += fswap16(sv);
      sv += fswap8(sv);
      sv += fswap4(sv);
      sv = DPPADD(sv, 0x4E);
      sv = DPPADD(sv, 0xB1);
      float mun = sv / 32.0f;
      float dv = (lane < NTOP) ? (v - mun) : 0.0f;
      float s2 = dv*dv;
      s2 += fswap32(s2);
      s2 += fswap16(s2);
      s2 += fswap8(s2);
      s2 += fswap4(s2);
      s2 = DPPADD(s2, 0x4E);
      s2 = DPPADD(s2, 0xB1);
      float stdv = sqrtf(s2 / 31.0f);
      if (t == 98){
        if (lane == 0) out[b] = mun * 6.2831854820251465f;  // fp32(2*pi)
      } else if (lane < MCAND){
        float e = EPSG ? EPB[(t&1)*MCAND + lane] : EPB[lane];
        AQ[lane] = fmaf(stdv, e, mun);                      // a(t+1)
      }
    } else if (!EPSG && wv == 7 && t < EPS_ROWS){
      uint32_t nt = (uint32_t)(t + 1);
      { uint32_t i0 = 2u*nt;      uint32_t ii = (i0 < 99u) ? i0 : (i0 - 99u);
        uint32_t x,y; tf2x32(A1k,B1k, ii, 99u+ii, x, y); kk0 = (i0 < 99u) ? x : y; }
      { uint32_t i1 = 2u*nt + 1u; uint32_t ii = (i1 < 99u) ? i1 : (i1 - 99u);
        uint32_t x,y; tf2x32(A1k,B1k, ii, 99u+ii, x, y); kk1 = (i1 < 99u) ? x : y; }
    }
    __syncthreads();   // B2: a(t+1) visible
  }
}

extern "C" void kernel_launch(void* const* d_in, const int* in_sizes, int n_in,
                              void* d_out, int out_size, void* d_ws, size_t ws_size,
                              hipStream_t stream) {
  const float* states = (const float*)d_in[0];
  const float* W1     = (const float*)d_in[1];
  const float* b1     = (const float*)d_in[2];
  const float* W2     = (const float*)d_in[3];
  const float* b2     = (const float*)d_in[4];
  const float* W3     = (const float*)d_in[5];
  const float* b3     = (const float*)d_in[6];
  float* out = (float*)d_out;

  if (d_ws != nullptr && ws_size >= WS_NEED){
    uint32_t* K = (uint32_t*)d_ws;
    float*    E = (float*)((char*)d_ws + 1024);
    hipLaunchKernelGGL(keys_kernel, dim3(1), dim3(128), 0, stream, K);
    hipLaunchKernelGGL(eps_kernel, dim3(EPS_ROWS*102400/256), dim3(256), 0, stream, K, E);
    hipLaunchKernelGGL(HIP_KERNEL_NAME(cem_kernel<true>), dim3(BATCH), dim3(512), 0, stream,
                       states, W1, b1, W2, b2, W3, b3, (const float*)E, out);
  } else {
    hipLaunchKernelGGL(HIP_KERNEL_NAME(cem_kernel<false>), dim3(BATCH), dim3(512), 0, stream,
                       states, W1, b1, W2, b2, W3, b3, (const float*)nullptr, out);
  }
}

// Round 10
// 1242.651 us; speedup vs baseline: 1.2010x; 1.0563x over previous
//
#include <hip/hip_runtime.h>
#include <math.h>
#include <stdint.h>

#define BATCH 4096
#define MCAND 50
#define NTOP 32
#define HID 100
#define TFL 20200                  /* floats per (T1,T2) table: 101*100*2 */
#define EPS_ROWS 98
#define EPS_ROWSZ (BATCH*MCAND)              /* 204800 */
#define WS_NEED   (1024u + (size_t)EPS_ROWS*EPS_ROWSZ*4u)

#define MINVC  (-0x1.fffffep-1f)   /* nextafter(-1,0) */
#define SQRT2C (0x1.6a09e6p+0f)    /* fp32 sqrt(2) */

__device__ __forceinline__ uint32_t rotl32(uint32_t v, int d){ return (v<<d)|(v>>(32-d)); }

// JAX threefry2x32 core (20 rounds, 5 key injections)
__device__ __forceinline__ void tf2x32(uint32_t k0, uint32_t k1, uint32_t x0, uint32_t x1,
                                       uint32_t &o0, uint32_t &o1){
  uint32_t k2 = k0 ^ k1 ^ 0x1BD11BDAu;
  x0 += k0; x1 += k1;
#define RND(r) { x0 += x1; x1 = rotl32(x1,(r)); x1 ^= x0; }
  RND(13) RND(15) RND(26) RND(6)
  x0 += k1; x1 += k2 + 1u;
  RND(17) RND(29) RND(16) RND(24)
  x0 += k2; x1 += k0 + 2u;
  RND(13) RND(15) RND(26) RND(6)
  x0 += k0; x1 += k1 + 3u;
  RND(17) RND(29) RND(16) RND(24)
  x0 += k1; x1 += k2 + 4u;
  RND(13) RND(15) RND(26) RND(6)
  x0 += k2; x1 += k0 + 5u;
#undef RND
  o0 = x0; o1 = x1;
}

// XLA ErfInv32 (Giles). w = -log1p(-x*x)
__device__ __forceinline__ float erfinv32(float x){
  float w = -log1pf(-x*x);
  float p;
  if (w < 5.0f){
    w = w - 2.5f;
    p = 2.81022636e-08f;
    p = fmaf(p, w, 3.43273939e-07f);
    p = fmaf(p, w, -3.5233877e-06f);
    p = fmaf(p, w, -4.39150654e-06f);
    p = fmaf(p, w, 0.00021858087f);
    p = fmaf(p, w, -0.00125372503f);
    p = fmaf(p, w, -0.00417768164f);
    p = fmaf(p, w, 0.246640727f);
    p = fmaf(p, w, 1.50140941f);
  } else {
    w = sqrtf(w) - 3.0f;
    p = -0.000200214257f;
    p = fmaf(p, w, 0.000100950558f);
    p = fmaf(p, w, 0.00134934322f);
    p = fmaf(p, w, -0.00367342844f);
    p = fmaf(p, w, 0.00573950773f);
    p = fmaf(p, w, -0.0076224613f);
    p = fmaf(p, w, 0.00943887047f);
    p = fmaf(p, w, 1.00167406f);
    p = fmaf(p, w, 2.83297682f);
  }
  return p*x;
}

// ---- VALU-only lane exchanges (no DS pipe) ----
#define DPPF(v, CTRL) __int_as_float(__builtin_amdgcn_update_dpp( \
    0, __float_as_int(v), (CTRL), 0xF, 0xF, true))
#define DPPI(v, CTRL) __builtin_amdgcn_update_dpp(0, (v), (CTRL), 0xF, 0xF, true)
#define DPPADD(v, CTRL) ((v) + DPPF((v), (CTRL)))

__device__ __forceinline__ float fswap4(float v){        // v[lane^4]
  float a = DPPF(v, 0x114);   // row_shr:4
  float b = DPPF(v, 0x104);   // row_shl:4
  return (threadIdx.x & 4) ? a : b;
}
__device__ __forceinline__ int iswap4(int v){
  int a = DPPI(v, 0x114), b = DPPI(v, 0x104);
  return (threadIdx.x & 4) ? a : b;
}
__device__ __forceinline__ float fswap8(float v){        // v[lane^8] = row_ror:8
  return DPPF(v, 0x128);
}
__device__ __forceinline__ float fswap16(float v){       // v[lane^16]
#if __has_builtin(__builtin_amdgcn_permlane16_swap)
  auto r = __builtin_amdgcn_permlane16_swap(__float_as_uint(v), __float_as_uint(v), false, false);
  return __uint_as_float((threadIdx.x & 16) ? r[0] : r[1]);
#else
  return __shfl_xor(v, 16, 64);
#endif
}
__device__ __forceinline__ float fswap32(float v){       // v[lane^32]
#if __has_builtin(__builtin_amdgcn_permlane32_swap)
  auto r = __builtin_amdgcn_permlane32_swap(__float_as_uint(v), __float_as_uint(v), false, false);
  return __uint_as_float((threadIdx.x & 32) ? r[0] : r[1]);
#else
  return __shfl_xor(v, 32, 64);
#endif
}

// ---------------------------------------------------------------------------
// Pre-kernels (r8): one thread produces TWO eps values (threefry r0 -> g,
// r1 -> g+102400). Layout [t][g]; in-loop row load is 50 contiguous floats.
// ---------------------------------------------------------------------------
__global__ void keys_kernel(uint32_t* __restrict__ K){
  int tid = threadIdx.x;
  if (tid < 99){
    uint32_t A0, B0, A1, B1;
    tf2x32(0u,42u,0u,2u,A0,A1);
    tf2x32(0u,42u,1u,3u,B0,B1);
    (void)A0; (void)B0;
    uint32_t o0,o1;
    tf2x32(A1,B1,(uint32_t)tid,(uint32_t)(99+tid),o0,o1);
    K[tid]    = o0;
    K[99+tid] = o1;
  }
}

__device__ __forceinline__ float bits2norm(uint32_t bits){
  float fl = __uint_as_float((bits>>9) | 0x3f800000u) - 1.0f;
  float u  = fmaxf(MINVC, fl*2.0f + MINVC);
  return SQRT2C * erfinv32(u);
}

__global__ __launch_bounds__(256) void eps_kernel(const uint32_t* __restrict__ K,
                                                  float* __restrict__ E){
  int id = blockIdx.x*256 + threadIdx.x;     // 98 * 102400 threads
  int t  = id / 102400;
  int g  = id - t*102400;
  uint32_t kk0 = K[2*t], kk1 = K[2*t+1];
  uint32_t r0, r1;
  tf2x32(kk0,kk1,(uint32_t)g,(uint32_t)g+102400u,r0,r1);
  E[(size_t)t*EPS_ROWSZ + g]           = bits2norm(r0);
  E[(size_t)t*EPS_ROWSZ + g + 102400]  = bits2norm(r1);
}

// ---------------------------------------------------------------------------
// Piecewise-linear CEM — r9 + ANTI-PHASE dephasing of co-resident blocks.
//
// Evidence chain: r2 (replicated stats, 1 barrier) ran at 90% VALUBusy
// (~160us stall); centralized-stats rounds (r3..r9) all sit at 42-58% busy
// with ~2200cyc/pair stall that ignored issue cuts (r8), eps-load removal
// (r7), and prefetch (r9). Diagnosis: the two co-resident blocks start
// synchronized and have identical iteration periods -> they phase-lock
// IN-PHASE: both collapse to their 1-wave stats chain simultaneously
// (possibly on the same SIMD), and both gather phases contend.
// Fix (zero numerics impact):
//   1. blocks with ((b>>8)&1) sleep ~960cy (half an iteration) after init --
//      co-resident pairs under round-robin dispatch are {b, b+256}, so this
//      seeds a persistent anti-phase offset (identical periods keep it).
//   2. s_setprio(1) around wave0's stats chain so the serial bitonic issues
//      promptly against the partner block's 7 gather waves (role-split).
// ---------------------------------------------------------------------------
template<bool EPSG>
__global__ __launch_bounds__(512) void cem_kernel(
    const float* __restrict__ states, const float* __restrict__ W1,
    const float* __restrict__ b1,     const float* __restrict__ W2,
    const float* __restrict__ b2,     const float* __restrict__ W3,
    const float* __restrict__ b3,     const float* __restrict__ epsg,
    float* __restrict__ out)
{
  __shared__ __align__(16) float smem[20350];           // 81,400 B
  float*  const Tb   = smem;                            // table region
  float2* const T2D  = (float2*)Tb;                     // [101][100] (T1,T2)
  int*    const ORD  = (int*)(Tb + 300);                // init scratch (in T)
  float*  const STm  = Tb + 400;                        // init scratch (in T)
  float*  const AQ   = smem + 20200;                    // [50] angles <-> q
  float*  const EPB  = smem + 20250;                    // [2][50] eps ping-pong

  const int tid  = threadIdx.x;
  const int b    = blockIdx.x;
  const int wv   = tid >> 6;
  const int lane = tid & 63;
  const int gc   = tid >> 3;            // gather candidate (8 lanes/cand)
  const int gj   = tid & 7;
  const bool gact = (tid < 8*MCAND);    // tid < 400 (waves 0-6)

  // per-thread W3 slice for the gather (n = gj + 8i)
  float w3r[13];
#pragma unroll
  for (int i = 0; i < 13; ++i){
    int n = gj + (i<<3);
    w3r[i] = (n < HID) ? W3[n] : 0.0f;
  }
  const float sB3v = b3[0];

  // fallback-path wave7 register state
  uint32_t A1k = 0u, B1k = 0u, kk0 = 0u, kk1 = 0u;

  // ---------- init P0: u,v,thresholds; angles0; (fallback) key state ----------
  if (tid < HID){
    float u = fmaf(states[2*b], W1[tid], fmaf(states[2*b+1], W1[HID+tid], b1[tid]));
    float v = W1[2*HID+tid];
    float tt = (v != 0.0f) ? (-u / v) : INFINITY;
    Tb[tid]     = u;
    Tb[HID+tid] = v;
    Tb[200+tid] = tt;
  }
  if (tid >= 128 && tid < 128 + MCAND){
    // iteration-0 uniform angles (mu=0, std=1)
    int c = tid - 128;
    uint32_t A0, B0, a1t, b1t;
    tf2x32(0u,42u,0u,2u,A0,a1t);
    tf2x32(0u,42u,1u,3u,B0,b1t);
    uint32_t gidx = (uint32_t)b*MCAND + (uint32_t)c;
    uint32_t r0,r1,bits;
    if (gidx < 102400u){ tf2x32(A0,B0,gidx,gidx+102400u,r0,r1); bits = r0; }
    else               { tf2x32(A0,B0,gidx-102400u,gidx,r0,r1); bits = r1; }
    AQ[c] = __uint_as_float((bits>>9) | 0x3f800000u) - 1.0f;
  }
  if (!EPSG && wv == 7){
    uint32_t A0, B0;
    tf2x32(0u,42u,0u,2u,A0,A1k);
    tf2x32(0u,42u,1u,3u,B0,B1k);
    { uint32_t i0 = 0u; uint32_t x,y; tf2x32(A1k,B1k, i0, 99u+i0, x, y); kk0 = x; }
    { uint32_t i1 = 1u; uint32_t x,y; tf2x32(A1k,B1k, i1, 99u+i1, x, y); kk1 = x; }
  }
  __syncthreads();

  // ---------- init P1: stable rank-by-count, scatter sorted ----------
  if (tid < HID){
    float tk = Tb[200+tid];
    int rk = 0;
    for (int j2 = 0; j2 < HID; ++j2){
      float tj = Tb[200+j2];
      rk += (tj < tk || (tj == tk && j2 < tid)) ? 1 : 0;
    }
    float u = Tb[tid], v = Tb[HID+tid];
    // neg-type: active iff a < t (v<0, or v==0 with u>0 -> always active, t=+inf)
    int neg = (v < 0.0f || (v == 0.0f && u > 0.0f)) ? 1 : 0;
    STm[rk] = tk;
    ORD[rk] = tid | (neg << 7);
  }
  __syncthreads();

  // ---------- init P1.5: builder meta -> regs (wave0); thresholds -> regs ----------
  int kpA = 0, kpB = 0; float cuA = 0.f, cvA = 0.f, cuB = 0.f, cvB = 0.f;
  if (wv == 0){
    kpA = ORD[lane];
    int kiA = kpA & 127;
    float uA = Tb[kiA], vA = Tb[HID+kiA];
    cuA = (kpA & 128) ? -uA : uA;     // signed delta for prefix pass
    cvA = (kpA & 128) ? -vA : vA;
    if (lane < 36){
      kpB = ORD[64+lane];
      int kiB = kpB & 127;
      float uB = Tb[kiB], vB = Tb[HID+kiB];
      cuB = (kpB & 128) ? -uB : uB;
      cvB = (kpB & 128) ? -vB : vB;
    }
  }
  float st_r[13];                       // loop-invariant thresholds in regs
#pragma unroll
  for (int i = 0; i < 13; ++i){
    int idx = gj*13 + i;
    st_r[i] = (idx < HID) ? STm[idx] : INFINITY;
  }
  __syncthreads();   // meta/thresholds consumed; T scratch region now dead

  // ---------- init P2: wave0 builds the 101-row prefix table ----------
  if (wv == 0){
    const int L = lane;          // columns n=L and n=64+L (L<36)
    float a10 = b2[L], a20 = 0.0f;
    float a11 = (L < 36) ? b2[64+L] : 0.0f, a21 = 0.0f;
    // pass 1: rank-0 base = b2 + sum over neg-type features of (+u,+v)*W2row
#pragma unroll 8
    for (int rr = 0; rr < 64; ++rr){
      int   kp = __builtin_amdgcn_readlane(kpA, rr);
      float cu = __int_as_float(__builtin_amdgcn_readlane(__float_as_int(cuA), rr));
      float cv = __int_as_float(__builtin_amdgcn_readlane(__float_as_int(cvA), rr));
      int k = kp & 127;
      float bu = (kp & 128) ? -cu : 0.0f;  // = +u for neg-type, 0 for pos-type
      float bv = (kp & 128) ? -cv : 0.0f;
      float w0 = W2[k*HID + L];
      a10 = fmaf(bu, w0, a10); a20 = fmaf(bv, w0, a20);
      if (L < 36){
        float w1 = W2[k*HID + 64+L];
        a11 = fmaf(bu, w1, a11); a21 = fmaf(bv, w1, a21);
      }
    }
#pragma unroll 6
    for (int rr = 0; rr < 36; ++rr){
      int   kp = __builtin_amdgcn_readlane(kpB, rr);
      float cu = __int_as_float(__builtin_amdgcn_readlane(__float_as_int(cuB), rr));
      float cv = __int_as_float(__builtin_amdgcn_readlane(__float_as_int(cvB), rr));
      int k = kp & 127;
      float bu = (kp & 128) ? -cu : 0.0f;
      float bv = (kp & 128) ? -cv : 0.0f;
      float w0 = W2[k*HID + L];
      a10 = fmaf(bu, w0, a10); a20 = fmaf(bv, w0, a20);
      if (L < 36){
        float w1 = W2[k*HID + 64+L];
        a11 = fmaf(bu, w1, a11); a21 = fmaf(bv, w1, a21);
      }
    }
    { float2 f; f.x = a10; f.y = a20; T2D[L] = f; }
    if (L < 36){ float2 f; f.x = a11; f.y = a21; T2D[64+L] = f; }
    // pass 2: ascending ranks, signed deltas, write T[rr+1]
#pragma unroll 8
    for (int rr = 0; rr < 64; ++rr){
      int   kp = __builtin_amdgcn_readlane(kpA, rr);
      float cu = __int_as_float(__builtin_amdgcn_readlane(__float_as_int(cuA), rr));
      float cv = __int_as_float(__builtin_amdgcn_readlane(__float_as_int(cvA), rr));
      int k = kp & 127;
      float w0 = W2[k*HID + L];
      a10 = fmaf(cu, w0, a10); a20 = fmaf(cv, w0, a20);
      { float2 f; f.x = a10; f.y = a20; T2D[(rr+1)*HID + L] = f; }
      if (L < 36){
        float w1 = W2[k*HID + 64+L];
        a11 = fmaf(cu, w1, a11); a21 = fmaf(cv, w1, a21);
        float2 f; f.x = a11; f.y = a21; T2D[(rr+1)*HID + 64+L] = f;
      }
    }
#pragma unroll 6
    for (int rr = 0; rr < 36; ++rr){
      int   kp = __builtin_amdgcn_readlane(kpB, rr);
      float cu = __int_as_float(__builtin_amdgcn_readlane(__float_as_int(cuB), rr));
      float cv = __int_as_float(__builtin_amdgcn_readlane(__float_as_int(cvB), rr));
      int k = kp & 127;
      float w0 = W2[k*HID + L];
      a10 = fmaf(cu, w0, a10); a20 = fmaf(cv, w0, a20);
      { float2 f; f.x = a10; f.y = a20; T2D[(65+rr)*HID + L] = f; }
      if (L < 36){
        float w1 = W2[k*HID + 64+L];
        a11 = fmaf(cu, w1, a11); a21 = fmaf(cv, w1, a21);
        float2 f; f.x = a11; f.y = a21; T2D[(65+rr)*HID + 64+L] = f;
      }
    }
  }

  // ---------- eps prefetch prologue (wave7, EPSG): row0 -> EPB[0]; issue row1 ----------
  float pref = 0.0f;
  if (EPSG && wv == 7 && lane < MCAND){
    const float* Eb = epsg + (size_t)b*MCAND + (size_t)lane;
    EPB[lane] = Eb[0];                         // row 0 (one-time synchronous)
    pref = Eb[(size_t)1*EPS_ROWSZ];            // row 1 issued; waited at t=0
  }
  __syncthreads();   // table + angles0 + eps row0 visible

  // ---------- ANTI-PHASE: offset the second co-resident stream ~960 cyc ----------
  // Round-robin dispatch pairs blocks {b, b+256} on a CU; ((b>>8)&1) selects
  // one of the pair. Identical per-iteration periods preserve the offset, so
  // block A's 1-wave stats chain overlaps block B's 7-wave gather thereafter.
  if ((b >> 8) & 1) __builtin_amdgcn_s_sleep(15);

  // ---------- CEM loop: 99 evaluations ----------
#pragma unroll 1
  for (int t = 0; t < 99; ++t){
    // --- G: q_c = sum_n relu(T1[r][n] + a*T2[r][n]) * W3[n] ---
    if (gact){
      const float av = AQ[gc];            // LDS broadcast (8 lanes same addr)
      int rk = 0;
#pragma unroll
      for (int i = 0; i < 13; ++i) rk += (st_r[i] < av) ? 1 : 0;
      rk += DPPI(rk, 0xB1);
      rk += DPPI(rk, 0x4E);
      rk += iswap4(rk);
      // stride-uniform addressing: byte base once, imm-offset b64 reads
      const char* rowp = (const char*)T2D + (((rk*HID) + gj) << 3);
      float acc = 0.0f;
#pragma unroll
      for (int i = 0; i < 12; ++i){
        float2 tv = *(const float2*)(rowp + (i << 6));   // n = gj + 8i
        float h = fmaxf(fmaf(av, tv.y, tv.x), 0.0f);
        acc = fmaf(h, w3r[i], acc);
      }
      if (gj < 4){                        // tail n = 96+gj (others added +0)
        float2 tv = *(const float2*)(rowp + (12 << 6));
        float h = fmaxf(fmaf(av, tv.y, tv.x), 0.0f);
        acc = fmaf(h, w3r[12], acc);
      }
      acc = DPPADD(acc, 0xB1);
      acc = DPPADD(acc, 0x4E);
      acc += fswap4(acc);
      if (gj == 0) AQ[gc] = acc;          // q overwrites a (own group's slot)
    }
    // --- eps staging: write prefetched row t+1, issue row t+2 (no wait) ---
    if (EPSG){
      if (wv == 7 && lane < MCAND && (t+1) < EPS_ROWS){
        EPB[((t+1)&1)*MCAND + lane] = pref;   // vmcnt wait: 1 full iter of slack
        if ((t+2) < EPS_ROWS)
          pref = epsg[(size_t)(t+2)*EPS_ROWSZ + (size_t)b*MCAND + (size_t)lane];
      }
    } else if (wv == 7 && t < EPS_ROWS && lane < MCAND){
      uint32_t gidx = (uint32_t)b*MCAND + (uint32_t)lane;
      uint32_t r0, r1, bits;
      if (gidx < 102400u){ tf2x32(kk0,kk1,gidx,gidx+102400u,r0,r1); bits = r0; }
      else               { tf2x32(kk0,kk1,gidx-102400u,gidx,r0,r1); bits = r1; }
      EPB[lane] = bits2norm(bits);
    }
    __syncthreads();   // B1: q(t) + eps row visible

    // --- S: wave0 stats (prio-boosted); (fallback) wave7 computes kk(t+1) ---
    if (wv == 0){
      __builtin_amdgcn_s_setprio(1);
      float q = (lane < MCAND) ? (AQ[lane] + sB3v) : -INFINITY;
      // sort 32-halves in opposite directions, j=32 max-merge -> top-32 multiset
      float v = q;
#define BST(KK, JJ, PV) { float pv = (PV); bool lower = (lane & (JJ)) == 0; \
        bool asc = (lane & (KK)) != 0; float mn = fminf(v, pv), mx = fmaxf(v, pv); \
        v = (lower == asc) ? mn : mx; }
      BST(2, 1,  DPPF(v, 0xB1))
      BST(4, 2,  DPPF(v, 0x4E))
      BST(4, 1,  DPPF(v, 0xB1))
      BST(8, 4,  fswap4(v))
      BST(8, 2,  DPPF(v, 0x4E))
      BST(8, 1,  DPPF(v, 0xB1))
      BST(16, 8, fswap8(v))
      BST(16, 4, fswap4(v))
      BST(16, 2, DPPF(v, 0x4E))
      BST(16, 1, DPPF(v, 0xB1))
      BST(32, 16, fswap16(v))
      BST(32, 8,  fswap8(v))
      BST(32, 4,  fswap4(v))
      BST(32, 2,  DPPF(v, 0x4E))
      BST(32, 1,  DPPF(v, 0xB1))
#undef BST
      {
        float pv = fswap32(v);
        v = ((lane & 32) == 0) ? fmaxf(v, pv) : fminf(v, pv);
      }
      // sum / sum-of-squares over lanes 0..31 (same add order as r2..r9)
      float sv = (lane < NTOP) ? v : 0.0f;
      sv += fswap32(sv);
      sv += fswap16(sv);
      sv += fswap8(sv);
      sv += fswap4(sv);
      sv = DPPADD(sv, 0x4E);
      sv = DPPADD(sv, 0xB1);
      float mun = sv / 32.0f;
      float dv = (lane < NTOP) ? (v - mun) : 0.0f;
      float s2 = dv*dv;
      s2 += fswap32(s2);
      s2 += fswap16(s2);
      s2 += fswap8(s2);
      s2 += fswap4(s2);
      s2 = DPPADD(s2, 0x4E);
      s2 = DPPADD(s2, 0xB1);
      float stdv = sqrtf(s2 / 31.0f);
      if (t == 98){
        if (lane == 0) out[b] = mun * 6.2831854820251465f;  // fp32(2*pi)
      } else if (lane < MCAND){
        float e = EPSG ? EPB[(t&1)*MCAND + lane] : EPB[lane];
        AQ[lane] = fmaf(stdv, e, mun);                      // a(t+1)
      }
      __builtin_amdgcn_s_setprio(0);
    } else if (!EPSG && wv == 7 && t < EPS_ROWS){
      uint32_t nt = (uint32_t)(t + 1);
      { uint32_t i0 = 2u*nt;      uint32_t ii = (i0 < 99u) ? i0 : (i0 - 99u);
        uint32_t x,y; tf2x32(A1k,B1k, ii, 99u+ii, x, y); kk0 = (i0 < 99u) ? x : y; }
      { uint32_t i1 = 2u*nt + 1u; uint32_t ii = (i1 < 99u) ? i1 : (i1 - 99u);
        uint32_t x,y; tf2x32(A1k,B1k, ii, 99u+ii, x, y); kk1 = (i1 < 99u) ? x : y; }
    }
    __syncthreads();   // B2: a(t+1) visible
  }
}

extern "C" void kernel_launch(void* const* d_in, const int* in_sizes, int n_in,
                              void* d_out, int out_size, void* d_ws, size_t ws_size,
                              hipStream_t stream) {
  const float* states = (const float*)d_in[0];
  const float* W1     = (const float*)d_in[1];
  const float* b1     = (const float*)d_in[2];
  const float* W2     = (const float*)d_in[3];
  const float* b2     = (const float*)d_in[4];
  const float* W3     = (const float*)d_in[5];
  const float* b3     = (const float*)d_in[6];
  float* out = (float*)d_out;

  if (d_ws != nullptr && ws_size >= WS_NEED){
    uint32_t* K = (uint32_t*)d_ws;
    float*    E = (float*)((char*)d_ws + 1024);
    hipLaunchKernelGGL(keys_kernel, dim3(1), dim3(128), 0, stream, K);
    hipLaunchKernelGGL(eps_kernel, dim3(EPS_ROWS*102400/256), dim3(256), 0, stream, K, E);
    hipLaunchKernelGGL(HIP_KERNEL_NAME(cem_kernel<true>), dim3(BATCH), dim3(512), 0, stream,
                       states, W1, b1, W2, b2, W3, b3, (const float*)E, out);
  } else {
    hipLaunchKernelGGL(HIP_KERNEL_NAME(cem_kernel<false>), dim3(BATCH), dim3(512), 0, stream,
                       states, W1, b1, W2, b2, W3, b3, (const float*)nullptr, out);
  }
}

// Round 11
// 1232.614 us; speedup vs baseline: 1.2108x; 1.0081x over previous
//
#include <hip/hip_runtime.h>
#include <math.h>
#include <stdint.h>

#define BATCH 4096
#define MCAND 50
#define NTOP 32
#define HID 100
#define TFL 20200                  /* floats per (T1,T2) table: 101*100*2 */
#define EPS_ROWS 98
#define EPS_ROWSZ (BATCH*MCAND)              /* 204800 */
#define WS_NEED   (1024u + (size_t)EPS_ROWS*EPS_ROWSZ*4u)

#define MINVC  (-0x1.fffffep-1f)   /* nextafter(-1,0) */
#define SQRT2C (0x1.6a09e6p+0f)    /* fp32 sqrt(2) */

__device__ __forceinline__ uint32_t rotl32(uint32_t v, int d){ return (v<<d)|(v>>(32-d)); }

// JAX threefry2x32 core (20 rounds, 5 key injections)
__device__ __forceinline__ void tf2x32(uint32_t k0, uint32_t k1, uint32_t x0, uint32_t x1,
                                       uint32_t &o0, uint32_t &o1){
  uint32_t k2 = k0 ^ k1 ^ 0x1BD11BDAu;
  x0 += k0; x1 += k1;
#define RND(r) { x0 += x1; x1 = rotl32(x1,(r)); x1 ^= x0; }
  RND(13) RND(15) RND(26) RND(6)
  x0 += k1; x1 += k2 + 1u;
  RND(17) RND(29) RND(16) RND(24)
  x0 += k2; x1 += k0 + 2u;
  RND(13) RND(15) RND(26) RND(6)
  x0 += k0; x1 += k1 + 3u;
  RND(17) RND(29) RND(16) RND(24)
  x0 += k1; x1 += k2 + 4u;
  RND(13) RND(15) RND(26) RND(6)
  x0 += k2; x1 += k0 + 5u;
#undef RND
  o0 = x0; o1 = x1;
}

// XLA ErfInv32 (Giles). w = -log1p(-x*x)
__device__ __forceinline__ float erfinv32(float x){
  float w = -log1pf(-x*x);
  float p;
  if (w < 5.0f){
    w = w - 2.5f;
    p = 2.81022636e-08f;
    p = fmaf(p, w, 3.43273939e-07f);
    p = fmaf(p, w, -3.5233877e-06f);
    p = fmaf(p, w, -4.39150654e-06f);
    p = fmaf(p, w, 0.00021858087f);
    p = fmaf(p, w, -0.00125372503f);
    p = fmaf(p, w, -0.00417768164f);
    p = fmaf(p, w, 0.246640727f);
    p = fmaf(p, w, 1.50140941f);
  } else {
    w = sqrtf(w) - 3.0f;
    p = -0.000200214257f;
    p = fmaf(p, w, 0.000100950558f);
    p = fmaf(p, w, 0.00134934322f);
    p = fmaf(p, w, -0.00367342844f);
    p = fmaf(p, w, 0.00573950773f);
    p = fmaf(p, w, -0.0076224613f);
    p = fmaf(p, w, 0.00943887047f);
    p = fmaf(p, w, 1.00167406f);
    p = fmaf(p, w, 2.83297682f);
  }
  return p*x;
}

// ---- VALU-only lane exchanges (no DS pipe) ----
#define DPPF(v, CTRL) __int_as_float(__builtin_amdgcn_update_dpp( \
    0, __float_as_int(v), (CTRL), 0xF, 0xF, true))
#define DPPI(v, CTRL) __builtin_amdgcn_update_dpp(0, (v), (CTRL), 0xF, 0xF, true)
#define DPPADD(v, CTRL) ((v) + DPPF((v), (CTRL)))

__device__ __forceinline__ float fswap4(float v){        // v[lane^4]
  float a = DPPF(v, 0x114);   // row_shr:4
  float b = DPPF(v, 0x104);   // row_shl:4
  return (threadIdx.x & 4) ? a : b;
}
__device__ __forceinline__ int iswap4(int v){
  int a = DPPI(v, 0x114), b = DPPI(v, 0x104);
  return (threadIdx.x & 4) ? a : b;
}
__device__ __forceinline__ float fswap8(float v){        // v[lane^8] = row_ror:8
  return DPPF(v, 0x128);
}
__device__ __forceinline__ float fswap16(float v){       // v[lane^16]
#if __has_builtin(__builtin_amdgcn_permlane16_swap)
  auto r = __builtin_amdgcn_permlane16_swap(__float_as_uint(v), __float_as_uint(v), false, false);
  return __uint_as_float((threadIdx.x & 16) ? r[0] : r[1]);
#else
  return __shfl_xor(v, 16, 64);
#endif
}
__device__ __forceinline__ float fswap32(float v){       // v[lane^32]
#if __has_builtin(__builtin_amdgcn_permlane32_swap)
  auto r = __builtin_amdgcn_permlane32_swap(__float_as_uint(v), __float_as_uint(v), false, false);
  return __uint_as_float((threadIdx.x & 32) ? r[0] : r[1]);
#else
  return __shfl_xor(v, 32, 64);
#endif
}

// LDS-only barrier: s_waitcnt lgkmcnt(0) + s_barrier, WITHOUT the vmcnt(0)
// drain __syncthreads() emits. In-flight global loads (register-private eps)
// cross the barrier; the compiler inserts the vmcnt wait at first USE.
// This is the CDNA counted-vmcnt pattern (T4): r9's register prefetch was
// nullified exactly because __syncthreads force-drained it each iteration.
__device__ __forceinline__ void bar_lgkm(){
  asm volatile("s_waitcnt lgkmcnt(0)\n\ts_barrier" ::: "memory");
}

// ---------------------------------------------------------------------------
// Pre-kernels (r8): one thread produces TWO eps values (threefry r0 -> g,
// r1 -> g+102400). Layout [t][g]; in-loop row load is 50 contiguous floats.
// ---------------------------------------------------------------------------
__global__ void keys_kernel(uint32_t* __restrict__ K){
  int tid = threadIdx.x;
  if (tid < 99){
    uint32_t A0, B0, A1, B1;
    tf2x32(0u,42u,0u,2u,A0,A1);
    tf2x32(0u,42u,1u,3u,B0,B1);
    (void)A0; (void)B0;
    uint32_t o0,o1;
    tf2x32(A1,B1,(uint32_t)tid,(uint32_t)(99+tid),o0,o1);
    K[tid]    = o0;
    K[99+tid] = o1;
  }
}

__device__ __forceinline__ float bits2norm(uint32_t bits){
  float fl = __uint_as_float((bits>>9) | 0x3f800000u) - 1.0f;
  float u  = fmaxf(MINVC, fl*2.0f + MINVC);
  return SQRT2C * erfinv32(u);
}

__global__ __launch_bounds__(256) void eps_kernel(const uint32_t* __restrict__ K,
                                                  float* __restrict__ E){
  int id = blockIdx.x*256 + threadIdx.x;     // 98 * 102400 threads
  int t  = id / 102400;
  int g  = id - t*102400;
  uint32_t kk0 = K[2*t], kk1 = K[2*t+1];
  uint32_t r0, r1;
  tf2x32(kk0,kk1,(uint32_t)g,(uint32_t)g+102400u,r0,r1);
  E[(size_t)t*EPS_ROWSZ + g]           = bits2norm(r0);
  E[(size_t)t*EPS_ROWSZ + g + 102400]  = bits2norm(r1);
}

// ---------------------------------------------------------------------------
// Piecewise-linear CEM — r10 + vmcnt-preserving barriers.
//
// Root cause of r3..r9's ~500-900cy/iter stall (finally identified):
// __syncthreads() emits `s_waitcnt vmcnt(0)` per-wave, so the wave issuing
// the eps global load arrives at B1 only after the full HBM latency — every
// iteration, holding all 16 waves. r9's register prefetch was nullified by
// this drain (load issued right before the barrier that drains it).
// Fix: (1) loop barriers become lgkmcnt-only raw s_barrier (LDS ordering for
// AQ/EPB is fully covered; the eps value is register-private and needs no
// barrier visibility); (2) wave0 loads its own eps row at loop top, consumed
// in S after B1 -> latency hidden under gather+barrier with no forced drain.
// Wave7 has no loop role (EPSG). Dephasing + setprio kept (r10: +6%).
// ---------------------------------------------------------------------------
template<bool EPSG>
__global__ __launch_bounds__(512) void cem_kernel(
    const float* __restrict__ states, const float* __restrict__ W1,
    const float* __restrict__ b1,     const float* __restrict__ W2,
    const float* __restrict__ b2,     const float* __restrict__ W3,
    const float* __restrict__ b3,     const float* __restrict__ epsg,
    float* __restrict__ out)
{
  __shared__ __align__(16) float smem[20300];           // 81,200 B
  float*  const Tb   = smem;                            // table region
  float2* const T2D  = (float2*)Tb;                     // [101][100] (T1,T2)
  int*    const ORD  = (int*)(Tb + 300);                // init scratch (in T)
  float*  const STm  = Tb + 400;                        // init scratch (in T)
  float*  const AQ   = smem + 20200;                    // [50] angles <-> q
  float*  const EPB  = smem + 20250;                    // [50] eps (fallback)

  const int tid  = threadIdx.x;
  const int b    = blockIdx.x;
  const int wv   = tid >> 6;
  const int lane = tid & 63;
  const int gc   = tid >> 3;            // gather candidate (8 lanes/cand)
  const int gj   = tid & 7;
  const bool gact = (tid < 8*MCAND);    // tid < 400 (waves 0-6)

  // per-thread W3 slice for the gather (n = gj + 8i)
  float w3r[13];
#pragma unroll
  for (int i = 0; i < 13; ++i){
    int n = gj + (i<<3);
    w3r[i] = (n < HID) ? W3[n] : 0.0f;
  }
  const float sB3v = b3[0];

  // fallback-path wave7 register state
  uint32_t A1k = 0u, B1k = 0u, kk0 = 0u, kk1 = 0u;

  // ---------- init P0: u,v,thresholds; angles0; (fallback) key state ----------
  if (tid < HID){
    float u = fmaf(states[2*b], W1[tid], fmaf(states[2*b+1], W1[HID+tid], b1[tid]));
    float v = W1[2*HID+tid];
    float tt = (v != 0.0f) ? (-u / v) : INFINITY;
    Tb[tid]     = u;
    Tb[HID+tid] = v;
    Tb[200+tid] = tt;
  }
  if (tid >= 128 && tid < 128 + MCAND){
    // iteration-0 uniform angles (mu=0, std=1)
    int c = tid - 128;
    uint32_t A0, B0, a1t, b1t;
    tf2x32(0u,42u,0u,2u,A0,a1t);
    tf2x32(0u,42u,1u,3u,B0,b1t);
    uint32_t gidx = (uint32_t)b*MCAND + (uint32_t)c;
    uint32_t r0,r1,bits;
    if (gidx < 102400u){ tf2x32(A0,B0,gidx,gidx+102400u,r0,r1); bits = r0; }
    else               { tf2x32(A0,B0,gidx-102400u,gidx,r0,r1); bits = r1; }
    AQ[c] = __uint_as_float((bits>>9) | 0x3f800000u) - 1.0f;
  }
  if (!EPSG && wv == 7){
    uint32_t A0, B0;
    tf2x32(0u,42u,0u,2u,A0,A1k);
    tf2x32(0u,42u,1u,3u,B0,B1k);
    { uint32_t i0 = 0u; uint32_t x,y; tf2x32(A1k,B1k, i0, 99u+i0, x, y); kk0 = x; }
    { uint32_t i1 = 1u; uint32_t x,y; tf2x32(A1k,B1k, i1, 99u+i1, x, y); kk1 = x; }
  }
  __syncthreads();

  // ---------- init P1: stable rank-by-count, scatter sorted ----------
  if (tid < HID){
    float tk = Tb[200+tid];
    int rk = 0;
    for (int j2 = 0; j2 < HID; ++j2){
      float tj = Tb[200+j2];
      rk += (tj < tk || (tj == tk && j2 < tid)) ? 1 : 0;
    }
    float u = Tb[tid], v = Tb[HID+tid];
    // neg-type: active iff a < t (v<0, or v==0 with u>0 -> always active, t=+inf)
    int neg = (v < 0.0f || (v == 0.0f && u > 0.0f)) ? 1 : 0;
    STm[rk] = tk;
    ORD[rk] = tid | (neg << 7);
  }
  __syncthreads();

  // ---------- init P1.5: builder meta -> regs (wave0); thresholds -> regs ----------
  int kpA = 0, kpB = 0; float cuA = 0.f, cvA = 0.f, cuB = 0.f, cvB = 0.f;
  if (wv == 0){
    kpA = ORD[lane];
    int kiA = kpA & 127;
    float uA = Tb[kiA], vA = Tb[HID+kiA];
    cuA = (kpA & 128) ? -uA : uA;     // signed delta for prefix pass
    cvA = (kpA & 128) ? -vA : vA;
    if (lane < 36){
      kpB = ORD[64+lane];
      int kiB = kpB & 127;
      float uB = Tb[kiB], vB = Tb[HID+kiB];
      cuB = (kpB & 128) ? -uB : uB;
      cvB = (kpB & 128) ? -vB : vB;
    }
  }
  float st_r[13];                       // loop-invariant thresholds in regs
#pragma unroll
  for (int i = 0; i < 13; ++i){
    int idx = gj*13 + i;
    st_r[i] = (idx < HID) ? STm[idx] : INFINITY;
  }
  __syncthreads();   // meta/thresholds consumed; T scratch region now dead

  // ---------- init P2: wave0 builds the 101-row prefix table ----------
  if (wv == 0){
    const int L = lane;          // columns n=L and n=64+L (L<36)
    float a10 = b2[L], a20 = 0.0f;
    float a11 = (L < 36) ? b2[64+L] : 0.0f, a21 = 0.0f;
    // pass 1: rank-0 base = b2 + sum over neg-type features of (+u,+v)*W2row
#pragma unroll 8
    for (int rr = 0; rr < 64; ++rr){
      int   kp = __builtin_amdgcn_readlane(kpA, rr);
      float cu = __int_as_float(__builtin_amdgcn_readlane(__float_as_int(cuA), rr));
      float cv = __int_as_float(__builtin_amdgcn_readlane(__float_as_int(cvA), rr));
      int k = kp & 127;
      float bu = (kp & 128) ? -cu : 0.0f;  // = +u for neg-type, 0 for pos-type
      float bv = (kp & 128) ? -cv : 0.0f;
      float w0 = W2[k*HID + L];
      a10 = fmaf(bu, w0, a10); a20 = fmaf(bv, w0, a20);
      if (L < 36){
        float w1 = W2[k*HID + 64+L];
        a11 = fmaf(bu, w1, a11); a21 = fmaf(bv, w1, a21);
      }
    }
#pragma unroll 6
    for (int rr = 0; rr < 36; ++rr){
      int   kp = __builtin_amdgcn_readlane(kpB, rr);
      float cu = __int_as_float(__builtin_amdgcn_readlane(__float_as_int(cuB), rr));
      float cv = __int_as_float(__builtin_amdgcn_readlane(__float_as_int(cvB), rr));
      int k = kp & 127;
      float bu = (kp & 128) ? -cu : 0.0f;
      float bv = (kp & 128) ? -cv : 0.0f;
      float w0 = W2[k*HID + L];
      a10 = fmaf(bu, w0, a10); a20 = fmaf(bv, w0, a20);
      if (L < 36){
        float w1 = W2[k*HID + 64+L];
        a11 = fmaf(bu, w1, a11); a21 = fmaf(bv, w1, a21);
      }
    }
    { float2 f; f.x = a10; f.y = a20; T2D[L] = f; }
    if (L < 36){ float2 f; f.x = a11; f.y = a21; T2D[64+L] = f; }
    // pass 2: ascending ranks, signed deltas, write T[rr+1]
#pragma unroll 8
    for (int rr = 0; rr < 64; ++rr){
      int   kp = __builtin_amdgcn_readlane(kpA, rr);
      float cu = __int_as_float(__builtin_amdgcn_readlane(__float_as_int(cuA), rr));
      float cv = __int_as_float(__builtin_amdgcn_readlane(__float_as_int(cvA), rr));
      int k = kp & 127;
      float w0 = W2[k*HID + L];
      a10 = fmaf(cu, w0, a10); a20 = fmaf(cv, w0, a20);
      { float2 f; f.x = a10; f.y = a20; T2D[(rr+1)*HID + L] = f; }
      if (L < 36){
        float w1 = W2[k*HID + 64+L];
        a11 = fmaf(cu, w1, a11); a21 = fmaf(cv, w1, a21);
        float2 f; f.x = a11; f.y = a21; T2D[(rr+1)*HID + 64+L] = f;
      }
    }
#pragma unroll 6
    for (int rr = 0; rr < 36; ++rr){
      int   kp = __builtin_amdgcn_readlane(kpB, rr);
      float cu = __int_as_float(__builtin_amdgcn_readlane(__float_as_int(cuB), rr));
      float cv = __int_as_float(__builtin_amdgcn_readlane(__float_as_int(cvB), rr));
      int k = kp & 127;
      float w0 = W2[k*HID + L];
      a10 = fmaf(cu, w0, a10); a20 = fmaf(cv, w0, a20);
      { float2 f; f.x = a10; f.y = a20; T2D[(65+rr)*HID + L] = f; }
      if (L < 36){
        float w1 = W2[k*HID + 64+L];
        a11 = fmaf(cu, w1, a11); a21 = fmaf(cv, w1, a21);
        float2 f; f.x = a11; f.y = a21; T2D[(65+rr)*HID + 64+L] = f;
      }
    }
  }
  __syncthreads();   // table + angles0 visible (full drain: init has VMEM)

  // ---------- ANTI-PHASE: offset the second co-resident stream ~960 cyc ----------
  if ((b >> 8) & 1) __builtin_amdgcn_s_sleep(15);

  // ---------- CEM loop: 99 evaluations ----------
#pragma unroll 1
  for (int t = 0; t < 99; ++t){
    // --- wave0: issue eps row t load FIRST (consumed in S after B1; the
    //     lgkm-only barrier lets it stay in flight -> latency hidden) ---
    float epsv = 0.0f;
    if (EPSG && wv == 0 && lane < MCAND && t < EPS_ROWS)
      epsv = epsg[(size_t)t*EPS_ROWSZ + (size_t)b*MCAND + (size_t)lane];

    // --- G: q_c = sum_n relu(T1[r][n] + a*T2[r][n]) * W3[n] ---
    if (gact){
      const float av = AQ[gc];            // LDS broadcast (8 lanes same addr)
      int rk = 0;
#pragma unroll
      for (int i = 0; i < 13; ++i) rk += (st_r[i] < av) ? 1 : 0;
      rk += DPPI(rk, 0xB1);
      rk += DPPI(rk, 0x4E);
      rk += iswap4(rk);
      // stride-uniform addressing: byte base once, imm-offset b64 reads
      const char* rowp = (const char*)T2D + (((rk*HID) + gj) << 3);
      float acc = 0.0f;
#pragma unroll
      for (int i = 0; i < 12; ++i){
        float2 tv = *(const float2*)(rowp + (i << 6));   // n = gj + 8i
        float h = fmaxf(fmaf(av, tv.y, tv.x), 0.0f);
        acc = fmaf(h, w3r[i], acc);
      }
      if (gj < 4){                        // tail n = 96+gj (others added +0)
        float2 tv = *(const float2*)(rowp + (12 << 6));
        float h = fmaxf(fmaf(av, tv.y, tv.x), 0.0f);
        acc = fmaf(h, w3r[12], acc);
      }
      acc = DPPADD(acc, 0xB1);
      acc = DPPADD(acc, 0x4E);
      acc += fswap4(acc);
      if (gj == 0) AQ[gc] = acc;          // q overwrites a (own group's slot)
    }
    // --- fallback: per-iter eps on wave 7 (VALU only, LDS write) ---
    if (!EPSG && wv == 7 && t < EPS_ROWS && lane < MCAND){
      uint32_t gidx = (uint32_t)b*MCAND + (uint32_t)lane;
      uint32_t r0, r1, bits;
      if (gidx < 102400u){ tf2x32(kk0,kk1,gidx,gidx+102400u,r0,r1); bits = r0; }
      else               { tf2x32(kk0,kk1,gidx-102400u,gidx,r0,r1); bits = r1; }
      EPB[lane] = bits2norm(bits);
    }
    bar_lgkm();        // B1: q(t) (+fallback eps) visible; eps load in flight

    // --- S: wave0 stats (prio-boosted); (fallback) wave7 computes kk(t+1) ---
    if (wv == 0){
      __builtin_amdgcn_s_setprio(1);
      float q = (lane < MCAND) ? (AQ[lane] + sB3v) : -INFINITY;
      // sort 32-halves in opposite directions, j=32 max-merge -> top-32 multiset
      float v = q;
#define BST(KK, JJ, PV) { float pv = (PV); bool lower = (lane & (JJ)) == 0; \
        bool asc = (lane & (KK)) != 0; float mn = fminf(v, pv), mx = fmaxf(v, pv); \
        v = (lower == asc) ? mn : mx; }
      BST(2, 1,  DPPF(v, 0xB1))
      BST(4, 2,  DPPF(v, 0x4E))
      BST(4, 1,  DPPF(v, 0xB1))
      BST(8, 4,  fswap4(v))
      BST(8, 2,  DPPF(v, 0x4E))
      BST(8, 1,  DPPF(v, 0xB1))
      BST(16, 8, fswap8(v))
      BST(16, 4, fswap4(v))
      BST(16, 2, DPPF(v, 0x4E))
      BST(16, 1, DPPF(v, 0xB1))
      BST(32, 16, fswap16(v))
      BST(32, 8,  fswap8(v))
      BST(32, 4,  fswap4(v))
      BST(32, 2,  DPPF(v, 0x4E))
      BST(32, 1,  DPPF(v, 0xB1))
#undef BST
      {
        float pv = fswap32(v);
        v = ((lane & 32) == 0) ? fmaxf(v, pv) : fminf(v, pv);
      }
      // sum / sum-of-squares over lanes 0..31 (same add order as r2..r10)
      float sv = (lane < NTOP) ? v : 0.0f;
      sv += fswap32(sv);
      sv += fswap16(sv);
      sv += fswap8(sv);
      sv += fswap4(sv);
      sv = DPPADD(sv, 0x4E);
      sv = DPPADD(sv, 0xB1);
      float mun = sv / 32.0f;
      float dv = (lane < NTOP) ? (v - mun) : 0.0f;
      float s2 = dv*dv;
      s2 += fswap32(s2);
      s2 += fswap16(s2);
      s2 += fswap8(s2);
      s2 += fswap4(s2);
      s2 = DPPADD(s2, 0x4E);
      s2 = DPPADD(s2, 0xB1);
      float stdv = sqrtf(s2 / 31.0f);
      if (t == 98){
        if (lane == 0) out[b] = mun * 6.2831854820251465f;  // fp32(2*pi)
      } else if (lane < MCAND){
        float e = EPSG ? epsv : EPB[lane];   // vmcnt wait lands HERE (hidden)
        AQ[lane] = fmaf(stdv, e, mun);       // a(t+1)
      }
      __builtin_amdgcn_s_setprio(0);
    } else if (!EPSG && wv == 7 && t < EPS_ROWS){
      uint32_t nt = (uint32_t)(t + 1);
      { uint32_t i0 = 2u*nt;      uint32_t ii = (i0 < 99u) ? i0 : (i0 - 99u);
        uint32_t x,y; tf2x32(A1k,B1k, ii, 99u+ii, x, y); kk0 = (i0 < 99u) ? x : y; }
      { uint32_t i1 = 2u*nt + 1u; uint32_t ii = (i1 < 99u) ? i1 : (i1 - 99u);
        uint32_t x,y; tf2x32(A1k,B1k, ii, 99u+ii, x, y); kk1 = (i1 < 99u) ? x : y; }
    }
    bar_lgkm();        // B2: a(t+1) visible
  }
}

extern "C" void kernel_launch(void* const* d_in, const int* in_sizes, int n_in,
                              void* d_out, int out_size, void* d_ws, size_t ws_size,
                              hipStream_t stream) {
  const float* states = (const float*)d_in[0];
  const float* W1     = (const float*)d_in[1];
  const float* b1     = (const float*)d_in[2];
  const float* W2     = (const float*)d_in[3];
  const float* b2     = (const float*)d_in[4];
  const float* W3     = (const float*)d_in[5];
  const float* b3     = (const float*)d_in[6];
  float* out = (float*)d_out;

  if (d_ws != nullptr && ws_size >= WS_NEED){
    uint32_t* K = (uint32_t*)d_ws;
    float*    E = (float*)((char*)d_ws + 1024);
    hipLaunchKernelGGL(keys_kernel, dim3(1), dim3(128), 0, stream, K);
    hipLaunchKernelGGL(eps_kernel, dim3(EPS_ROWS*102400/256), dim3(256), 0, stream, K, E);
    hipLaunchKernelGGL(HIP_KERNEL_NAME(cem_kernel<true>), dim3(BATCH), dim3(512), 0, stream,
                       states, W1, b1, W2, b2, W3, b3, (const float*)E, out);
  } else {
    hipLaunchKernelGGL(HIP_KERNEL_NAME(cem_kernel<false>), dim3(BATCH), dim3(512), 0, stream,
                       states, W1, b1, W2, b2, W3, b3, (const float*)nullptr, out);
  }
}